// Round 12
// baseline (160.433 us; speedup 1.0000x reference)
//
#include <hip/hip_runtime.h>
#include <hip/hip_bf16.h>
#include <math.h>

#define B 128
#define V 32
#define H 128
#define LDH 264    // h-region row pitch in bf16 elems (528 B)
#define NTHR 256

typedef __attribute__((ext_vector_type(8))) short bf16x8;
typedef __attribute__((ext_vector_type(4))) float f32x4;

// Swapped-operand layout: D = W_frag x Act_frag; lane owns batch row (lane&15)
// and 4 consecutive units ((lane>>4)*4 + reg).
__device__ inline f32x4 mfma_wx(bf16x8 wf, bf16x8 xf, f32x4 c) {
    return __builtin_amdgcn_mfma_f32_16x16x32_bf16(wf, xf, c, 0, 0, 0);
}
__device__ inline unsigned short f2bf(float f) {
    __hip_bfloat16 h = __float2bfloat16(f);
    return __builtin_bit_cast(unsigned short, h);
}
__device__ inline float bf2f(unsigned short u) {
    unsigned int x = ((unsigned int)u) << 16;
    return __builtin_bit_cast(float, x);
}
// pre-scaled activations: weights/biases for r,z carry -1/ln2, n carries 2/ln2
__device__ inline float sig_pre(float y)  { return __builtin_amdgcn_rcpf(1.f + __builtin_amdgcn_exp2f(y)); }
__device__ inline float tanh_pre(float y) { return 1.f - 2.f * __builtin_amdgcn_rcpf(__builtin_amdgcn_exp2f(y) + 1.f); }
__device__ inline bf16x8 load_xfrag(const float* p) {
    float4 a = *(const float4*)p;
    float4 b = *(const float4*)(p + 4);
    bf16x8 r;
    r[0] = (short)f2bf(a.x); r[1] = (short)f2bf(a.y);
    r[2] = (short)f2bf(a.z); r[3] = (short)f2bf(a.w);
    r[4] = (short)f2bf(b.x); r[5] = (short)f2bf(b.y);
    r[6] = (short)f2bf(b.z); r[7] = (short)f2bf(b.w);
    return r;
}
__device__ inline uint2 pack4(float a, float b, float c, float d) {
    uint2 r;
    r.x = (unsigned int)f2bf(a) | ((unsigned int)f2bf(b) << 16);
    r.y = (unsigned int)f2bf(c) | ((unsigned int)f2bf(d) << 16);
    return r;
}

// ---------------------------------------------------------------------------
// Pack GRU weights (PRE-SCALED) + proj weights into MFMA fragment order.
// ---------------------------------------------------------------------------
__global__ void prep_pack(const float* __restrict__ wir_w, const float* __restrict__ whr_w,
                          const float* __restrict__ wiz_w, const float* __restrict__ whz_w,
                          const float* __restrict__ win_w, const float* __restrict__ whn_w,
                          const float* __restrict__ wir_b, const float* __restrict__ whr_b,
                          const float* __restrict__ wiz_b, const float* __restrict__ whz_b,
                          const float* __restrict__ win_b, const float* __restrict__ whn_b,
                          const float* __restrict__ mu_w, const float* __restrict__ mu_b,
                          const float* __restrict__ lv_w, const float* __restrict__ lv_b,
                          unsigned short* __restrict__ wFrag, unsigned short* __restrict__ pFrag,
                          float* __restrict__ bias)
{
    int idx = blockIdx.x * blockDim.x + threadIdx.x;
    if (idx < 13824) {
        int lane = idx & 63;
        int ctks = idx >> 6;
        int ct = ctks % 24;
        int ks = ctks / 24;
        int g = ct >> 3;
        int t = ct & 7;
        int u = t * 16 + (lane & 15);
        const float scl = (g == 2) ? 2.88539008f : -1.44269504f;
        const float* wi = (g == 0) ? wir_w : (g == 1) ? wiz_w : win_w;
        const float* wh = (g == 0) ? whr_w : (g == 1) ? whz_w : whn_w;
        unsigned short v[8] __attribute__((aligned(16)));
        #pragma unroll
        for (int i = 0; i < 8; ++i) {
            float f;
            if (ks == 0) { int k = 8 * (lane >> 4) + i; f = wi[u * V + k]; }
            else         { int k = (ks - 1) * 32 + 8 * (lane >> 4) + i; f = wh[u * 256 + k]; }
            v[i] = f2bf(f * scl);
        }
        *(int4*)(wFrag + (size_t)idx * 8) = *(const int4*)v;
    } else if (idx < 13824 + 4096) {
        int pidx = idx - 13824;
        int lane = pidx & 63;
        int rest = pidx >> 6;
        int ct2 = rest & 15;
        int ks = rest >> 4;
        int sel = ct2 >> 3, tl = ct2 & 7;
        int u = tl * 16 + (lane & 15);
        const float* wsrc = sel ? lv_w : mu_w;
        unsigned short v[8] __attribute__((aligned(16)));
        #pragma unroll
        for (int i = 0; i < 8; ++i) {
            int k = ks * 32 + 8 * (lane >> 4) + i;
            v[i] = f2bf(wsrc[u * H + k]);
        }
        *(int4*)(pFrag + (size_t)pidx * 8) = *(const int4*)v;
    }
    if (idx < 6 * H) {
        int s = idx / H, u = idx % H;
        float val;
        if (s == 0)      val = (wir_b[u] + whr_b[u]) * -1.44269504f;
        else if (s == 1) val = (wiz_b[u] + whz_b[u]) * -1.44269504f;
        else if (s == 2) val = win_b[u] * 2.88539008f;
        else if (s == 3) val = whn_b[u] * 2.88539008f;
        else if (s == 4) val = mu_b[u];
        else             val = lv_b[u];
        bias[idx] = val;
    }
}

// ---------------------------------------------------------------------------
// Fused subtree kernel v3: levels leaf+9+8, t-unrolled accumulators, no
// weight/bias register caching (spill-safe via launch_bounds(.,3): cap 168).
// Grid 1024: block (n = d8 node, q = 32-row chunk). lvl9 never touches HBM.
// ---------------------------------------------------------------------------
__global__ __launch_bounds__(NTHR, 3) void subtree8_kernel(
    const float* __restrict__ targets, const float* __restrict__ masks,
    unsigned short* __restrict__ lvl8,
    const unsigned short* __restrict__ wFrag, const float* __restrict__ bias)
{
    __shared__ __attribute__((aligned(16))) unsigned short h_lds[32 * LDH];
    __shared__ __attribute__((aligned(16))) unsigned short h2_lds[32 * LDH];

    const int tid = threadIdx.x;
    const int lane = tid & 63;
    const int w = tid >> 6;
    const int l15 = lane & 15;
    const int lg = lane >> 4;
    const int n = blockIdx.x >> 2;
    const int q = blockIdx.x & 3;

    for (int half = 0; half < 2; ++half) {
        const int j = 2 * n + half;
        const size_t r9 = (size_t)(511 + j) * B + (size_t)q * 32;

        // ---- leaf children of j -> h_lds (K0 only) ----
        #pragma unroll
        for (int c = 0; c < 2; ++c) {
            const size_t crow = (size_t)(1023 + 2 * j + c) * B + (size_t)q * 32;
            bf16x8 xf0 = load_xfrag(targets + (crow + l15) * V + 8 * lg);
            bf16x8 xf1 = load_xfrag(targets + (crow + 16 + l15) * V + 8 * lg);
            float m0 = masks[crow + l15];
            float m1 = masks[crow + 16 + l15];
            f32x4 ar[2][2], az[2][2], an[2][2], bh[2];
            #pragma unroll
            for (int t = 0; t < 2; ++t) {
                int u0 = w * 32 + t * 16 + lg * 4;
                f32x4 b0 = *(const f32x4*)(bias + u0);
                f32x4 b1 = *(const f32x4*)(bias + 128 + u0);
                f32x4 b2 = *(const f32x4*)(bias + 256 + u0);
                bh[t]    = *(const f32x4*)(bias + 384 + u0);
                ar[0][t] = b0; ar[1][t] = b0;
                az[0][t] = b1; az[1][t] = b1;
                an[0][t] = b2; an[1][t] = b2;
            }
            #pragma unroll
            for (int t = 0; t < 2; ++t) {
                int tt = 2 * w + t;
                bf16x8 wr_ = *(const bf16x8*)(wFrag + ((size_t)(tt) * 64 + lane) * 8);
                bf16x8 wz_ = *(const bf16x8*)(wFrag + ((size_t)(8 + tt) * 64 + lane) * 8);
                bf16x8 wn_ = *(const bf16x8*)(wFrag + ((size_t)(16 + tt) * 64 + lane) * 8);
                ar[0][t] = mfma_wx(wr_, xf0, ar[0][t]);
                ar[1][t] = mfma_wx(wr_, xf1, ar[1][t]);
                az[0][t] = mfma_wx(wz_, xf0, az[0][t]);
                az[1][t] = mfma_wx(wz_, xf1, az[1][t]);
                an[0][t] = mfma_wx(wn_, xf0, an[0][t]);
                an[1][t] = mfma_wx(wn_, xf1, an[1][t]);
            }
            #pragma unroll
            for (int rt = 0; rt < 2; ++rt) {
                float m = rt ? m1 : m0;
                int row = rt * 16 + l15;
                #pragma unroll
                for (int t = 0; t < 2; ++t) {
                    int u0 = w * 32 + t * 16 + lg * 4;
                    float ho[4];
                    #pragma unroll
                    for (int reg = 0; reg < 4; ++reg) {
                        float rg = sig_pre(ar[rt][t][reg]);
                        float zg = sig_pre(az[rt][t][reg]);
                        float cg = tanh_pre(an[rt][t][reg] + rg * bh[t][reg]);
                        ho[reg] = (cg - zg * cg) * m;
                    }
                    *(uint2*)(&h_lds[row * LDH + c * 128 + u0]) = pack4(ho[0], ho[1], ho[2], ho[3]);
                }
            }
        }
        __syncthreads();   // h_lds (leaf h) ready

        // ---- d9 tile: K0 from x9, K1..8 from h_lds; out -> h2_lds ----
        {
            bf16x8 x9_0 = load_xfrag(targets + (r9 + l15) * V + 8 * lg);
            bf16x8 x9_1 = load_xfrag(targets + (r9 + 16 + l15) * V + 8 * lg);
            float m0 = masks[r9 + l15];
            float m1 = masks[r9 + 16 + l15];
            f32x4 acc_r[2][2], acc_z[2][2], acc_i[2][2], acc_h[2][2];
            #pragma unroll
            for (int t = 0; t < 2; ++t) {
                int u0 = w * 32 + t * 16 + lg * 4;
                f32x4 b0 = *(const f32x4*)(bias + u0);
                f32x4 b1 = *(const f32x4*)(bias + 128 + u0);
                f32x4 b2 = *(const f32x4*)(bias + 256 + u0);
                f32x4 b3 = *(const f32x4*)(bias + 384 + u0);
                acc_r[0][t] = b0; acc_r[1][t] = b0;
                acc_z[0][t] = b1; acc_z[1][t] = b1;
                acc_i[0][t] = b2; acc_i[1][t] = b2;
                acc_h[0][t] = b3; acc_h[1][t] = b3;
            }
            #pragma unroll
            for (int t = 0; t < 2; ++t) {
                int tt = 2 * w + t;
                bf16x8 wr_ = *(const bf16x8*)(wFrag + ((size_t)(tt) * 64 + lane) * 8);
                bf16x8 wz_ = *(const bf16x8*)(wFrag + ((size_t)(8 + tt) * 64 + lane) * 8);
                bf16x8 wn_ = *(const bf16x8*)(wFrag + ((size_t)(16 + tt) * 64 + lane) * 8);
                acc_r[0][t] = mfma_wx(wr_, x9_0, acc_r[0][t]);
                acc_r[1][t] = mfma_wx(wr_, x9_1, acc_r[1][t]);
                acc_z[0][t] = mfma_wx(wz_, x9_0, acc_z[0][t]);
                acc_z[1][t] = mfma_wx(wz_, x9_1, acc_z[1][t]);
                acc_i[0][t] = mfma_wx(wn_, x9_0, acc_i[0][t]);
                acc_i[1][t] = mfma_wx(wn_, x9_1, acc_i[1][t]);
            }
            #pragma unroll 2
            for (int ks = 1; ks <= 8; ++ks) {
                bf16x8 a0 = *(const bf16x8*)(&h_lds[l15 * LDH + (ks - 1) * 32 + 8 * lg]);
                bf16x8 a1 = *(const bf16x8*)(&h_lds[(16 + l15) * LDH + (ks - 1) * 32 + 8 * lg]);
                size_t fb = (size_t)ks * 24 * 64;
                #pragma unroll
                for (int t = 0; t < 2; ++t) {
                    int tt = 2 * w + t;
                    bf16x8 wr_ = *(const bf16x8*)(wFrag + (fb + (size_t)(tt) * 64 + lane) * 8);
                    bf16x8 wz_ = *(const bf16x8*)(wFrag + (fb + (size_t)(8 + tt) * 64 + lane) * 8);
                    bf16x8 wn_ = *(const bf16x8*)(wFrag + (fb + (size_t)(16 + tt) * 64 + lane) * 8);
                    acc_r[0][t] = mfma_wx(wr_, a0, acc_r[0][t]);
                    acc_r[1][t] = mfma_wx(wr_, a1, acc_r[1][t]);
                    acc_z[0][t] = mfma_wx(wz_, a0, acc_z[0][t]);
                    acc_z[1][t] = mfma_wx(wz_, a1, acc_z[1][t]);
                    acc_h[0][t] = mfma_wx(wn_, a0, acc_h[0][t]);
                    acc_h[1][t] = mfma_wx(wn_, a1, acc_h[1][t]);
                }
            }
            #pragma unroll
            for (int rt = 0; rt < 2; ++rt) {
                int row = rt * 16 + l15;
                float m = rt ? m1 : m0;
                #pragma unroll
                for (int t = 0; t < 2; ++t) {
                    int u0 = w * 32 + t * 16 + lg * 4;
                    ushort4 h1v = *(const ushort4*)(&h_lds[row * LDH + u0]);
                    ushort4 h2v = *(const ushort4*)(&h_lds[row * LDH + 128 + u0]);
                    const unsigned short* h1p = (const unsigned short*)&h1v;
                    const unsigned short* h2p = (const unsigned short*)&h2v;
                    float ho[4];
                    #pragma unroll
                    for (int reg = 0; reg < 4; ++reg) {
                        float rg = sig_pre(acc_r[rt][t][reg]);
                        float zg = sig_pre(acc_z[rt][t][reg]);
                        float cg = tanh_pre(acc_i[rt][t][reg] + rg * acc_h[rt][t][reg]);
                        float hm = 0.5f * bf2f(h1p[reg]) + 0.5f * bf2f(h2p[reg]);
                        ho[reg] = (cg + zg * (hm - cg)) * m;
                    }
                    *(uint2*)(&h2_lds[row * LDH + half * 128 + u0]) = pack4(ho[0], ho[1], ho[2], ho[3]);
                }
            }
        }
        __syncthreads();   // d9 reads of h_lds done; h2_lds writes visible
    }

    // ---- d8 tile: x8 + h2_lds -> global lvl8 ----
    {
        const size_t r8 = (size_t)(255 + n) * B + (size_t)q * 32;
        bf16x8 x8_0 = load_xfrag(targets + (r8 + l15) * V + 8 * lg);
        bf16x8 x8_1 = load_xfrag(targets + (r8 + 16 + l15) * V + 8 * lg);
        float m0 = masks[r8 + l15];
        float m1 = masks[r8 + 16 + l15];
        f32x4 acc_r[2][2], acc_z[2][2], acc_i[2][2], acc_h[2][2];
        #pragma unroll
        for (int t = 0; t < 2; ++t) {
            int u0 = w * 32 + t * 16 + lg * 4;
            f32x4 b0 = *(const f32x4*)(bias + u0);
            f32x4 b1 = *(const f32x4*)(bias + 128 + u0);
            f32x4 b2 = *(const f32x4*)(bias + 256 + u0);
            f32x4 b3 = *(const f32x4*)(bias + 384 + u0);
            acc_r[0][t] = b0; acc_r[1][t] = b0;
            acc_z[0][t] = b1; acc_z[1][t] = b1;
            acc_i[0][t] = b2; acc_i[1][t] = b2;
            acc_h[0][t] = b3; acc_h[1][t] = b3;
        }
        #pragma unroll
        for (int t = 0; t < 2; ++t) {
            int tt = 2 * w + t;
            bf16x8 wr_ = *(const bf16x8*)(wFrag + ((size_t)(tt) * 64 + lane) * 8);
            bf16x8 wz_ = *(const bf16x8*)(wFrag + ((size_t)(8 + tt) * 64 + lane) * 8);
            bf16x8 wn_ = *(const bf16x8*)(wFrag + ((size_t)(16 + tt) * 64 + lane) * 8);
            acc_r[0][t] = mfma_wx(wr_, x8_0, acc_r[0][t]);
            acc_r[1][t] = mfma_wx(wr_, x8_1, acc_r[1][t]);
            acc_z[0][t] = mfma_wx(wz_, x8_0, acc_z[0][t]);
            acc_z[1][t] = mfma_wx(wz_, x8_1, acc_z[1][t]);
            acc_i[0][t] = mfma_wx(wn_, x8_0, acc_i[0][t]);
            acc_i[1][t] = mfma_wx(wn_, x8_1, acc_i[1][t]);
        }
        #pragma unroll 2
        for (int ks = 1; ks <= 8; ++ks) {
            bf16x8 a0 = *(const bf16x8*)(&h2_lds[l15 * LDH + (ks - 1) * 32 + 8 * lg]);
            bf16x8 a1 = *(const bf16x8*)(&h2_lds[(16 + l15) * LDH + (ks - 1) * 32 + 8 * lg]);
            size_t fb = (size_t)ks * 24 * 64;
            #pragma unroll
            for (int t = 0; t < 2; ++t) {
                int tt = 2 * w + t;
                bf16x8 wr_ = *(const bf16x8*)(wFrag + (fb + (size_t)(tt) * 64 + lane) * 8);
                bf16x8 wz_ = *(const bf16x8*)(wFrag + (fb + (size_t)(8 + tt) * 64 + lane) * 8);
                bf16x8 wn_ = *(const bf16x8*)(wFrag + (fb + (size_t)(16 + tt) * 64 + lane) * 8);
                acc_r[0][t] = mfma_wx(wr_, a0, acc_r[0][t]);
                acc_r[1][t] = mfma_wx(wr_, a1, acc_r[1][t]);
                acc_z[0][t] = mfma_wx(wz_, a0, acc_z[0][t]);
                acc_z[1][t] = mfma_wx(wz_, a1, acc_z[1][t]);
                acc_h[0][t] = mfma_wx(wn_, a0, acc_h[0][t]);
                acc_h[1][t] = mfma_wx(wn_, a1, acc_h[1][t]);
            }
        }
        #pragma unroll
        for (int rt = 0; rt < 2; ++rt) {
            int row = rt * 16 + l15;
            float m = rt ? m1 : m0;
            #pragma unroll
            for (int t = 0; t < 2; ++t) {
                int u0 = w * 32 + t * 16 + lg * 4;
                ushort4 h1v = *(const ushort4*)(&h2_lds[row * LDH + u0]);
                ushort4 h2v = *(const ushort4*)(&h2_lds[row * LDH + 128 + u0]);
                const unsigned short* h1p = (const unsigned short*)&h1v;
                const unsigned short* h2p = (const unsigned short*)&h2v;
                float ho[4];
                #pragma unroll
                for (int reg = 0; reg < 4; ++reg) {
                    float rg = sig_pre(acc_r[rt][t][reg]);
                    float zg = sig_pre(acc_z[rt][t][reg]);
                    float cg = tanh_pre(acc_i[rt][t][reg] + rg * acc_h[rt][t][reg]);
                    float hm = 0.5f * bf2f(h1p[reg]) + 0.5f * bf2f(h2p[reg]);
                    ho[reg] = (cg + zg * (hm - cg)) * m;
                }
                *(uint2*)(lvl8 + ((size_t)n * B + (size_t)q * 32 + row) * H + u0) =
                    pack4(ho[0], ho[1], ho[2], ho[3]);
            }
        }
    }
}

// ---------------------------------------------------------------------------
// M=32 GRU tile (2 sibling nodes x 16 rows), LDS->LDS. hin: 32xLDH
// ([left-h | right-h] per node, rows 16*rt + r). hout write:
// hout[(rowbase + l15)*LDH + rt*128 + u0].
// ---------------------------------------------------------------------------
__device__ __forceinline__ void gru32_tile(
    const unsigned short* __restrict__ wFrag, const float* __restrict__ bias,
    bf16x8 xc0, bf16x8 xc1, float m0, float m1,
    const unsigned short* __restrict__ hin,
    unsigned short* __restrict__ hout, int rowbase,
    int lane, int w)
{
    const int l15 = lane & 15;
    const int lg = lane >> 4;
    f32x4 acc_r[2][2], acc_z[2][2], acc_i[2][2], acc_h[2][2];
    #pragma unroll
    for (int t = 0; t < 2; ++t) {
        int u0 = w * 32 + t * 16 + lg * 4;
        f32x4 b0 = *(const f32x4*)(bias + u0);
        f32x4 b1 = *(const f32x4*)(bias + 128 + u0);
        f32x4 b2 = *(const f32x4*)(bias + 256 + u0);
        f32x4 b3 = *(const f32x4*)(bias + 384 + u0);
        acc_r[0][t] = b0; acc_r[1][t] = b0;
        acc_z[0][t] = b1; acc_z[1][t] = b1;
        acc_i[0][t] = b2; acc_i[1][t] = b2;
        acc_h[0][t] = b3; acc_h[1][t] = b3;
    }
    #pragma unroll
    for (int t = 0; t < 2; ++t) {
        int tt = 2 * w + t;
        bf16x8 wr_ = *(const bf16x8*)(wFrag + ((size_t)(tt) * 64 + lane) * 8);
        bf16x8 wz_ = *(const bf16x8*)(wFrag + ((size_t)(8 + tt) * 64 + lane) * 8);
        bf16x8 wn_ = *(const bf16x8*)(wFrag + ((size_t)(16 + tt) * 64 + lane) * 8);
        acc_r[0][t] = mfma_wx(wr_, xc0, acc_r[0][t]);
        acc_r[1][t] = mfma_wx(wr_, xc1, acc_r[1][t]);
        acc_z[0][t] = mfma_wx(wz_, xc0, acc_z[0][t]);
        acc_z[1][t] = mfma_wx(wz_, xc1, acc_z[1][t]);
        acc_i[0][t] = mfma_wx(wn_, xc0, acc_i[0][t]);
        acc_i[1][t] = mfma_wx(wn_, xc1, acc_i[1][t]);
    }
    #pragma unroll 2
    for (int ks = 1; ks <= 8; ++ks) {
        bf16x8 a0 = *(const bf16x8*)(&hin[l15 * LDH + (ks - 1) * 32 + 8 * lg]);
        bf16x8 a1 = *(const bf16x8*)(&hin[(16 + l15) * LDH + (ks - 1) * 32 + 8 * lg]);
        size_t fb = (size_t)ks * 24 * 64;
        #pragma unroll
        for (int t = 0; t < 2; ++t) {
            int tt = 2 * w + t;
            bf16x8 wr_ = *(const bf16x8*)(wFrag + (fb + (size_t)(tt) * 64 + lane) * 8);
            bf16x8 wz_ = *(const bf16x8*)(wFrag + (fb + (size_t)(8 + tt) * 64 + lane) * 8);
            bf16x8 wn_ = *(const bf16x8*)(wFrag + (fb + (size_t)(16 + tt) * 64 + lane) * 8);
            acc_r[0][t] = mfma_wx(wr_, a0, acc_r[0][t]);
            acc_r[1][t] = mfma_wx(wr_, a1, acc_r[1][t]);
            acc_z[0][t] = mfma_wx(wz_, a0, acc_z[0][t]);
            acc_z[1][t] = mfma_wx(wz_, a1, acc_z[1][t]);
            acc_h[0][t] = mfma_wx(wn_, a0, acc_h[0][t]);
            acc_h[1][t] = mfma_wx(wn_, a1, acc_h[1][t]);
        }
    }
    #pragma unroll
    for (int rt = 0; rt < 2; ++rt) {
        float m = rt ? m1 : m0;
        int hrow = rt * 16 + l15;
        #pragma unroll
        for (int t = 0; t < 2; ++t) {
            int u0 = w * 32 + t * 16 + lg * 4;
            ushort4 h1v = *(const ushort4*)(&hin[hrow * LDH + u0]);
            ushort4 h2v = *(const ushort4*)(&hin[hrow * LDH + 128 + u0]);
            const unsigned short* h1p = (const unsigned short*)&h1v;
            const unsigned short* h2p = (const unsigned short*)&h2v;
            float ho[4];
            #pragma unroll
            for (int reg = 0; reg < 4; ++reg) {
                float rg = sig_pre(acc_r[rt][t][reg]);
                float zg = sig_pre(acc_z[rt][t][reg]);
                float cg = tanh_pre(acc_i[rt][t][reg] + rg * acc_h[rt][t][reg]);
                float hm = 0.5f * bf2f(h1p[reg]) + 0.5f * bf2f(h2p[reg]);
                ho[reg] = (cg + zg * (hm - cg)) * m;
            }
            *(uint2*)(&hout[(rowbase + l15) * LDH + rt * 128 + u0]) = pack4(ho[0], ho[1], ho[2], ho[3]);
        }
    }
}

// ---------------------------------------------------------------------------
// tail4: 4 tree levels dtop..dtop-3 of one (subtree root pr, 16-row chunk c8)
// chained through LDS. Only the bottom level's h touches global (or proj).
// Grid = (1 << (dtop-3)) * 8. s3..s0 = level start indices (host-computed).
// ---------------------------------------------------------------------------
__global__ __launch_bounds__(NTHR, 2) void tail4_kernel(
    const float* __restrict__ targets, const float* __restrict__ masks,
    const unsigned short* __restrict__ prev,     // level dtop+1 buffer
    unsigned short* __restrict__ outg,           // level dtop-3 buffer or null
    int s3, int s2, int s1, int s0,
    const unsigned short* __restrict__ wFrag, const float* __restrict__ bias,
    int do_proj, const unsigned short* __restrict__ pFrag, float* __restrict__ proj_out)
{
    __shared__ __attribute__((aligned(16))) unsigned short hc[32 * LDH];       // staging
    __shared__ __attribute__((aligned(16))) unsigned short h6[2 * 32 * LDH];   // dtop outputs
    __shared__ __attribute__((aligned(16))) unsigned short h5[32 * LDH];       // dtop-1 outputs
    __shared__ __attribute__((aligned(16))) unsigned short h4[16 * LDH];       // dtop-2 outputs

    const int tid = threadIdx.x;
    const int lane = tid & 63;
    const int w = tid >> 6;
    const int l15 = lane & 15;
    const int lg = lane >> 4;
    const int pr = blockIdx.x >> 3;
    const int c8 = blockIdx.x & 7;

    // ---- Phase 1: 4 x (stage from prev -> dtop M=32 tile -> h6) ----
    for (int s = 0; s < 4; ++s) {
        const int l1 = 4 * pr + s;   // node at level dtop-1
        #pragma unroll
        for (int t = 0; t < 4; ++t) {
            int task = t * NTHR + tid;
            int row = task >> 5;
            int ck = task & 31;
            int g = 4 * l1 + 2 * (row >> 4) + (ck >> 4);
            int4 v = *(const int4*)(prev + (((size_t)g) * B + (size_t)c8 * 16 + (row & 15)) * H + (ck & 15) * 8);
            *(int4*)(&hc[row * LDH + ck * 8]) = v;
        }
        size_t xr0 = ((size_t)(s3 + 2 * l1)) * B + (size_t)c8 * 16 + l15;
        size_t xr1 = ((size_t)(s3 + 2 * l1 + 1)) * B + (size_t)c8 * 16 + l15;
        bf16x8 xc0 = load_xfrag(targets + xr0 * V + 8 * lg);
        bf16x8 xc1 = load_xfrag(targets + xr1 * V + 8 * lg);
        float m0 = masks[xr0];
        float m1 = masks[xr1];
        __syncthreads();
        gru32_tile(wFrag, bias, xc0, xc1, m0, m1, hc,
                   h6 + (size_t)(s >> 1) * 32 * LDH, 16 * (s & 1), lane, w);
        __syncthreads();
    }

    // ---- Phase 2: 2 x (dtop-1 M=32 tile: h6[k] -> h5) ----
    for (int k = 0; k < 2; ++k) {
        int n1 = 4 * pr + 2 * k;
        size_t xr0 = ((size_t)(s2 + n1)) * B + (size_t)c8 * 16 + l15;
        size_t xr1 = ((size_t)(s2 + n1 + 1)) * B + (size_t)c8 * 16 + l15;
        bf16x8 xc0 = load_xfrag(targets + xr0 * V + 8 * lg);
        bf16x8 xc1 = load_xfrag(targets + xr1 * V + 8 * lg);
        float m0 = masks[xr0];
        float m1 = masks[xr1];
        gru32_tile(wFrag, bias, xc0, xc1, m0, m1,
                   h6 + (size_t)k * 32 * LDH, h5, 16 * k, lane, w);
    }
    __syncthreads();

    // ---- Phase 3: dtop-2 M=32 tile: h5 -> h4 ----
    {
        size_t xr0 = ((size_t)(s1 + 2 * pr)) * B + (size_t)c8 * 16 + l15;
        size_t xr1 = ((size_t)(s1 + 2 * pr + 1)) * B + (size_t)c8 * 16 + l15;
        bf16x8 xc0 = load_xfrag(targets + xr0 * V + 8 * lg);
        bf16x8 xc1 = load_xfrag(targets + xr1 * V + 8 * lg);
        float m0 = masks[xr0];
        float m1 = masks[xr1];
        gru32_tile(wFrag, bias, xc0, xc1, m0, m1, h5, h4, 0, lane, w);
    }
    __syncthreads();

    // ---- Phase 4: dtop-3 M=16 tile: h4 -> outg / proj ----
    {
        size_t xrp = ((size_t)(s0 + pr)) * B + (size_t)c8 * 16 + l15;
        bf16x8 xp = load_xfrag(targets + xrp * V + 8 * lg);
        float m = masks[xrp];
        f32x4 acc_r[2], acc_z[2], acc_i[2], acc_h[2];
        #pragma unroll
        for (int t = 0; t < 2; ++t) {
            int u0 = w * 32 + t * 16 + lg * 4;
            acc_r[t] = *(const f32x4*)(bias + u0);
            acc_z[t] = *(const f32x4*)(bias + 128 + u0);
            acc_i[t] = *(const f32x4*)(bias + 256 + u0);
            acc_h[t] = *(const f32x4*)(bias + 384 + u0);
        }
        #pragma unroll
        for (int t = 0; t < 2; ++t) {
            int tt = 2 * w + t;
            bf16x8 wr_ = *(const bf16x8*)(wFrag + ((size_t)(tt) * 64 + lane) * 8);
            bf16x8 wz_ = *(const bf16x8*)(wFrag + ((size_t)(8 + tt) * 64 + lane) * 8);
            bf16x8 wn_ = *(const bf16x8*)(wFrag + ((size_t)(16 + tt) * 64 + lane) * 8);
            acc_r[t] = mfma_wx(wr_, xp, acc_r[t]);
            acc_z[t] = mfma_wx(wz_, xp, acc_z[t]);
            acc_i[t] = mfma_wx(wn_, xp, acc_i[t]);
        }
        #pragma unroll 2
        for (int ks = 1; ks <= 8; ++ks) {
            bf16x8 a = *(const bf16x8*)(&h4[l15 * LDH + (ks - 1) * 32 + 8 * lg]);
            size_t fb = (size_t)ks * 24 * 64;
            #pragma unroll
            for (int t = 0; t < 2; ++t) {
                int tt = 2 * w + t;
                bf16x8 wr_ = *(const bf16x8*)(wFrag + (fb + (size_t)(tt) * 64 + lane) * 8);
                bf16x8 wz_ = *(const bf16x8*)(wFrag + (fb + (size_t)(8 + tt) * 64 + lane) * 8);
                bf16x8 wn_ = *(const bf16x8*)(wFrag + (fb + (size_t)(16 + tt) * 64 + lane) * 8);
                acc_r[t] = mfma_wx(wr_, a, acc_r[t]);
                acc_z[t] = mfma_wx(wz_, a, acc_z[t]);
                acc_h[t] = mfma_wx(wn_, a, acc_h[t]);
            }
        }
        #pragma unroll
        for (int t = 0; t < 2; ++t) {
            int u0 = w * 32 + t * 16 + lg * 4;
            ushort4 h1v = *(const ushort4*)(&h4[l15 * LDH + u0]);
            ushort4 h2v = *(const ushort4*)(&h4[l15 * LDH + 128 + u0]);
            const unsigned short* h1p = (const unsigned short*)&h1v;
            const unsigned short* h2p = (const unsigned short*)&h2v;
            float ho[4];
            #pragma unroll
            for (int reg = 0; reg < 4; ++reg) {
                float rg = sig_pre(acc_r[t][reg]);
                float zg = sig_pre(acc_z[t][reg]);
                float cg = tanh_pre(acc_i[t][reg] + rg * acc_h[t][reg]);
                float hm = 0.5f * bf2f(h1p[reg]) + 0.5f * bf2f(h2p[reg]);
                ho[reg] = (cg + zg * (hm - cg)) * m;
            }
            uint2 pk = pack4(ho[0], ho[1], ho[2], ho[3]);
            if (outg)
                *(uint2*)(outg + ((size_t)pr * B + (size_t)c8 * 16 + l15) * H + u0) = pk;
            if (do_proj)
                *(uint2*)(&hc[l15 * LDH + u0]) = pk;   // hc is dead; race-free proj input
        }
    }

    if (do_proj) {
        __syncthreads();
        f32x4 pa[4];
        #pragma unroll
        for (int jj = 0; jj < 4; ++jj) {
            int ct2 = 4 * w + jj;
            int sel = ct2 >> 3, tl = ct2 & 7;
            pa[jj] = *(const f32x4*)(bias + 512 + sel * 128 + tl * 16 + lg * 4);
        }
        #pragma unroll
        for (int ks = 0; ks < 4; ++ks) {
            bf16x8 a = *(const bf16x8*)(&hc[l15 * LDH + ks * 32 + 8 * lg]);
            #pragma unroll
            for (int jj = 0; jj < 4; ++jj) {
                bf16x8 f = *(const bf16x8*)(pFrag + (((size_t)ks * 16 + 4 * w + jj) * 64 + lane) * 8);
                pa[jj] = mfma_wx(f, a, pa[jj]);
            }
        }
        #pragma unroll
        for (int jj = 0; jj < 4; ++jj) {
            int ct2 = 4 * w + jj;
            int sel = ct2 >> 3, tl = ct2 & 7;
            int u0 = tl * 16 + lg * 4;
            int row = c8 * 16 + l15;
            *(f32x4*)(proj_out + ((size_t)sel * B + row) * H + u0) = pa[jj];
        }
    }
}

// ---------------------------------------------------------------------------
extern "C" void kernel_launch(void* const* d_in, const int* in_sizes, int n_in,
                              void* d_out, int out_size, void* d_ws, size_t ws_size,
                              hipStream_t stream)
{
    const float* targets = (const float*)d_in[0];
    const float* masks   = (const float*)d_in[1];
    const float* wir_w = (const float*)d_in[2];  const float* wir_b = (const float*)d_in[3];
    const float* whr_w = (const float*)d_in[4];  const float* whr_b = (const float*)d_in[5];
    const float* wiz_w = (const float*)d_in[6];  const float* wiz_b = (const float*)d_in[7];
    const float* whz_w = (const float*)d_in[8];  const float* whz_b = (const float*)d_in[9];
    const float* win_w = (const float*)d_in[10]; const float* win_b = (const float*)d_in[11];
    const float* whn_w = (const float*)d_in[12]; const float* whn_b = (const float*)d_in[13];
    const float* mu_w  = (const float*)d_in[14]; const float* mu_b  = (const float*)d_in[15];
    const float* lv_w  = (const float*)d_in[16]; const float* lv_b  = (const float*)d_in[17];

    unsigned short* ws16 = (unsigned short*)d_ws;
    unsigned short* lvl8 = ws16;                               // 256*128*128
    unsigned short* lvl4 = lvl8 + (size_t)256 * B * H;         // 16*128*128
    unsigned short* wFrag = lvl4 + (size_t)16 * B * H;         // 110592 bf16
    unsigned short* pFrag = wFrag + 110592;                    // 32768 bf16
    float*          biasw = (float*)(pFrag + 32768);           // 768 fp32

    prep_pack<<<70, 256, 0, stream>>>(
        wir_w, whr_w, wiz_w, whz_w, win_w, whn_w,
        wir_b, whr_b, wiz_b, whz_b, win_b, whn_b,
        mu_w, mu_b, lv_w, lv_b, wFrag, pFrag, biasw);

    subtree8_kernel<<<1024, NTHR, 0, stream>>>(targets, masks, lvl8, wFrag, biasw);

    // levels 7..4 (lvl8 -> lvl4), only lvl4 materialized
    tail4_kernel<<<128, NTHR, 0, stream>>>(
        targets, masks, lvl8, lvl4, 127, 63, 31, 15,
        wFrag, biasw, 0, nullptr, nullptr);

    // levels 3..0 + fused projection (lvl4 -> d_out)
    tail4_kernel<<<8, NTHR, 0, stream>>>(
        targets, masks, lvl4, nullptr, 7, 3, 1, 0,
        wFrag, biasw, 1, pFrag, (float*)d_out);
}

// Round 13
// 126.161 us; speedup vs baseline: 1.2716x; 1.2716x over previous
//
#include <hip/hip_runtime.h>
#include <hip/hip_bf16.h>
#include <math.h>

#define B 128
#define V 32
#define H 128
#define LDH 264    // h-region row pitch in bf16 elems (528 B)
#define NT 512     // 8 waves; each wave owns 16 units (tt = w)

typedef __attribute__((ext_vector_type(8))) short bf16x8;
typedef __attribute__((ext_vector_type(4))) float f32x4;

// Swapped-operand layout: D = W_frag x Act_frag; lane owns batch row (lane&15)
// and 4 consecutive units ((lane>>4)*4 + reg).
__device__ inline f32x4 mfma_wx(bf16x8 wf, bf16x8 xf, f32x4 c) {
    return __builtin_amdgcn_mfma_f32_16x16x32_bf16(wf, xf, c, 0, 0, 0);
}
__device__ inline unsigned short f2bf(float f) {
    __hip_bfloat16 h = __float2bfloat16(f);
    return __builtin_bit_cast(unsigned short, h);
}
__device__ inline float bf2f(unsigned short u) {
    unsigned int x = ((unsigned int)u) << 16;
    return __builtin_bit_cast(float, x);
}
// pre-scaled activations: weights/biases for r,z carry -1/ln2, n carries 2/ln2
__device__ inline float sig_pre(float y)  { return __builtin_amdgcn_rcpf(1.f + __builtin_amdgcn_exp2f(y)); }
__device__ inline float tanh_pre(float y) { return 1.f - 2.f * __builtin_amdgcn_rcpf(__builtin_amdgcn_exp2f(y) + 1.f); }
__device__ inline bf16x8 load_xfrag(const float* p) {
    float4 a = *(const float4*)p;
    float4 b = *(const float4*)(p + 4);
    bf16x8 r;
    r[0] = (short)f2bf(a.x); r[1] = (short)f2bf(a.y);
    r[2] = (short)f2bf(a.z); r[3] = (short)f2bf(a.w);
    r[4] = (short)f2bf(b.x); r[5] = (short)f2bf(b.y);
    r[6] = (short)f2bf(b.z); r[7] = (short)f2bf(b.w);
    return r;
}
__device__ inline uint2 pack4(float a, float b, float c, float d) {
    uint2 r;
    r.x = (unsigned int)f2bf(a) | ((unsigned int)f2bf(b) << 16);
    r.y = (unsigned int)f2bf(c) | ((unsigned int)f2bf(d) << 16);
    return r;
}

// ---------------------------------------------------------------------------
// Pack GRU weights (PRE-SCALED) + proj weights into MFMA fragment order.
// ---------------------------------------------------------------------------
__global__ void prep_pack(const float* __restrict__ wir_w, const float* __restrict__ whr_w,
                          const float* __restrict__ wiz_w, const float* __restrict__ whz_w,
                          const float* __restrict__ win_w, const float* __restrict__ whn_w,
                          const float* __restrict__ wir_b, const float* __restrict__ whr_b,
                          const float* __restrict__ wiz_b, const float* __restrict__ whz_b,
                          const float* __restrict__ win_b, const float* __restrict__ whn_b,
                          const float* __restrict__ mu_w, const float* __restrict__ mu_b,
                          const float* __restrict__ lv_w, const float* __restrict__ lv_b,
                          unsigned short* __restrict__ wFrag, unsigned short* __restrict__ pFrag,
                          float* __restrict__ bias)
{
    int idx = blockIdx.x * blockDim.x + threadIdx.x;
    if (idx < 13824) {
        int lane = idx & 63;
        int ctks = idx >> 6;
        int ct = ctks % 24;
        int ks = ctks / 24;
        int g = ct >> 3;
        int t = ct & 7;
        int u = t * 16 + (lane & 15);
        const float scl = (g == 2) ? 2.88539008f : -1.44269504f;
        const float* wi = (g == 0) ? wir_w : (g == 1) ? wiz_w : win_w;
        const float* wh = (g == 0) ? whr_w : (g == 1) ? whz_w : whn_w;
        unsigned short v[8] __attribute__((aligned(16)));
        #pragma unroll
        for (int i = 0; i < 8; ++i) {
            float f;
            if (ks == 0) { int k = 8 * (lane >> 4) + i; f = wi[u * V + k]; }
            else         { int k = (ks - 1) * 32 + 8 * (lane >> 4) + i; f = wh[u * 256 + k]; }
            v[i] = f2bf(f * scl);
        }
        *(int4*)(wFrag + (size_t)idx * 8) = *(const int4*)v;
    } else if (idx < 13824 + 4096) {
        int pidx = idx - 13824;
        int lane = pidx & 63;
        int rest = pidx >> 6;
        int ct2 = rest & 15;
        int ks = rest >> 4;
        int sel = ct2 >> 3, tl = ct2 & 7;
        int u = tl * 16 + (lane & 15);
        const float* wsrc = sel ? lv_w : mu_w;
        unsigned short v[8] __attribute__((aligned(16)));
        #pragma unroll
        for (int i = 0; i < 8; ++i) {
            int k = ks * 32 + 8 * (lane >> 4) + i;
            v[i] = f2bf(wsrc[u * H + k]);
        }
        *(int4*)(pFrag + (size_t)pidx * 8) = *(const int4*)v;
    }
    if (idx < 6 * H) {
        int s = idx / H, u = idx % H;
        float val;
        if (s == 0)      val = (wir_b[u] + whr_b[u]) * -1.44269504f;
        else if (s == 1) val = (wiz_b[u] + whz_b[u]) * -1.44269504f;
        else if (s == 2) val = win_b[u] * 2.88539008f;
        else if (s == 3) val = whn_b[u] * 2.88539008f;
        else if (s == 4) val = mu_b[u];
        else             val = lv_b[u];
        bias[idx] = val;
    }
}

// ---------------------------------------------------------------------------
// M=32 GRU tile body, 8-wave unit-split (wave w owns units [w*16, w*16+16)).
// K0 from x frags, K1..8 from hin (LDS). Per wave: 8 f32x4 acc (spill-free).
// Epilogue computes h_out and hands each 4-unit pack to `emit`.
// ---------------------------------------------------------------------------
template <typename EMIT>
__device__ __forceinline__ void gru32_body(
    const unsigned short* __restrict__ wFrag, const float* __restrict__ bias,
    bf16x8 x0, bf16x8 x1, float m0, float m1,
    const unsigned short* __restrict__ hin,
    int lane, int w, EMIT emit)
{
    const int l15 = lane & 15;
    const int lg = lane >> 4;
    const int u0 = w * 16 + lg * 4;

    f32x4 acc_r[2], acc_z[2], acc_i[2], acc_h[2];
    {
        f32x4 b0 = *(const f32x4*)(bias + u0);
        f32x4 b1 = *(const f32x4*)(bias + 128 + u0);
        f32x4 b2 = *(const f32x4*)(bias + 256 + u0);
        f32x4 b3 = *(const f32x4*)(bias + 384 + u0);
        acc_r[0] = b0; acc_r[1] = b0;
        acc_z[0] = b1; acc_z[1] = b1;
        acc_i[0] = b2; acc_i[1] = b2;
        acc_h[0] = b3; acc_h[1] = b3;
    }
    {
        bf16x8 wr_ = *(const bf16x8*)(wFrag + ((size_t)(w) * 64 + lane) * 8);
        bf16x8 wz_ = *(const bf16x8*)(wFrag + ((size_t)(8 + w) * 64 + lane) * 8);
        bf16x8 wn_ = *(const bf16x8*)(wFrag + ((size_t)(16 + w) * 64 + lane) * 8);
        acc_r[0] = mfma_wx(wr_, x0, acc_r[0]);
        acc_r[1] = mfma_wx(wr_, x1, acc_r[1]);
        acc_z[0] = mfma_wx(wz_, x0, acc_z[0]);
        acc_z[1] = mfma_wx(wz_, x1, acc_z[1]);
        acc_i[0] = mfma_wx(wn_, x0, acc_i[0]);
        acc_i[1] = mfma_wx(wn_, x1, acc_i[1]);
    }
    #pragma unroll 2
    for (int ks = 1; ks <= 8; ++ks) {
        bf16x8 a0 = *(const bf16x8*)(&hin[l15 * LDH + (ks - 1) * 32 + 8 * lg]);
        bf16x8 a1 = *(const bf16x8*)(&hin[(16 + l15) * LDH + (ks - 1) * 32 + 8 * lg]);
        size_t fb = (size_t)ks * 24 * 64;
        bf16x8 wr_ = *(const bf16x8*)(wFrag + (fb + (size_t)(w) * 64 + lane) * 8);
        bf16x8 wz_ = *(const bf16x8*)(wFrag + (fb + (size_t)(8 + w) * 64 + lane) * 8);
        bf16x8 wn_ = *(const bf16x8*)(wFrag + (fb + (size_t)(16 + w) * 64 + lane) * 8);
        acc_r[0] = mfma_wx(wr_, a0, acc_r[0]);
        acc_r[1] = mfma_wx(wr_, a1, acc_r[1]);
        acc_z[0] = mfma_wx(wz_, a0, acc_z[0]);
        acc_z[1] = mfma_wx(wz_, a1, acc_z[1]);
        acc_h[0] = mfma_wx(wn_, a0, acc_h[0]);
        acc_h[1] = mfma_wx(wn_, a1, acc_h[1]);
    }
    #pragma unroll
    for (int rt = 0; rt < 2; ++rt) {
        float m = rt ? m1 : m0;
        int hrow = rt * 16 + l15;
        ushort4 h1v = *(const ushort4*)(&hin[hrow * LDH + u0]);
        ushort4 h2v = *(const ushort4*)(&hin[hrow * LDH + 128 + u0]);
        const unsigned short* h1p = (const unsigned short*)&h1v;
        const unsigned short* h2p = (const unsigned short*)&h2v;
        float ho[4];
        #pragma unroll
        for (int reg = 0; reg < 4; ++reg) {
            float rg = sig_pre(acc_r[rt][reg]);
            float zg = sig_pre(acc_z[rt][reg]);
            float cg = tanh_pre(acc_i[rt][reg] + rg * acc_h[rt][reg]);
            float hm = 0.5f * bf2f(h1p[reg]) + 0.5f * bf2f(h2p[reg]);
            ho[reg] = (cg + zg * (hm - cg)) * m;
        }
        emit(rt, u0, pack4(ho[0], ho[1], ho[2], ho[3]));
    }
}

// ---------------------------------------------------------------------------
// Fused subtree kernel v4: levels leaf+9+8, 512 threads, 8-wave unit split.
// Grid 1024: block (n = d8 node, q = 32-row chunk). lvl9 never touches HBM.
// ---------------------------------------------------------------------------
__global__ __launch_bounds__(NT, 4) void subtree8_kernel(
    const float* __restrict__ targets, const float* __restrict__ masks,
    unsigned short* __restrict__ lvl8,
    const unsigned short* __restrict__ wFrag, const float* __restrict__ bias)
{
    __shared__ __attribute__((aligned(16))) unsigned short h_lds[32 * LDH];
    __shared__ __attribute__((aligned(16))) unsigned short h2_lds[32 * LDH];

    const int tid = threadIdx.x;
    const int lane = tid & 63;
    const int w = tid >> 6;
    const int l15 = lane & 15;
    const int lg = lane >> 4;
    const int u0 = w * 16 + lg * 4;
    const int n = blockIdx.x >> 2;
    const int q = blockIdx.x & 3;

    for (int half = 0; half < 2; ++half) {
        const int j = 2 * n + half;
        const size_t r9 = (size_t)(511 + j) * B + (size_t)q * 32;

        // ---- leaf children of j -> h_lds (K0 only; h1=h2=0) ----
        #pragma unroll
        for (int c = 0; c < 2; ++c) {
            const size_t crow = (size_t)(1023 + 2 * j + c) * B + (size_t)q * 32;
            bf16x8 xf0 = load_xfrag(targets + (crow + l15) * V + 8 * lg);
            bf16x8 xf1 = load_xfrag(targets + (crow + 16 + l15) * V + 8 * lg);
            float m0 = masks[crow + l15];
            float m1 = masks[crow + 16 + l15];
            f32x4 ar[2], az[2], an[2], bh;
            {
                f32x4 b0 = *(const f32x4*)(bias + u0);
                f32x4 b1 = *(const f32x4*)(bias + 128 + u0);
                f32x4 b2 = *(const f32x4*)(bias + 256 + u0);
                bh       = *(const f32x4*)(bias + 384 + u0);
                ar[0] = b0; ar[1] = b0;
                az[0] = b1; az[1] = b1;
                an[0] = b2; an[1] = b2;
            }
            {
                bf16x8 wr_ = *(const bf16x8*)(wFrag + ((size_t)(w) * 64 + lane) * 8);
                bf16x8 wz_ = *(const bf16x8*)(wFrag + ((size_t)(8 + w) * 64 + lane) * 8);
                bf16x8 wn_ = *(const bf16x8*)(wFrag + ((size_t)(16 + w) * 64 + lane) * 8);
                ar[0] = mfma_wx(wr_, xf0, ar[0]);
                ar[1] = mfma_wx(wr_, xf1, ar[1]);
                az[0] = mfma_wx(wz_, xf0, az[0]);
                az[1] = mfma_wx(wz_, xf1, az[1]);
                an[0] = mfma_wx(wn_, xf0, an[0]);
                an[1] = mfma_wx(wn_, xf1, an[1]);
            }
            #pragma unroll
            for (int rt = 0; rt < 2; ++rt) {
                float m = rt ? m1 : m0;
                int row = rt * 16 + l15;
                float ho[4];
                #pragma unroll
                for (int reg = 0; reg < 4; ++reg) {
                    float rg = sig_pre(ar[rt][reg]);
                    float zg = sig_pre(az[rt][reg]);
                    float cg = tanh_pre(an[rt][reg] + rg * bh[reg]);
                    ho[reg] = (cg - zg * cg) * m;
                }
                *(uint2*)(&h_lds[row * LDH + c * 128 + u0]) = pack4(ho[0], ho[1], ho[2], ho[3]);
            }
        }
        __syncthreads();   // h_lds (leaf h) ready

        // ---- d9 tile: out -> h2_lds ----
        {
            bf16x8 x9_0 = load_xfrag(targets + (r9 + l15) * V + 8 * lg);
            bf16x8 x9_1 = load_xfrag(targets + (r9 + 16 + l15) * V + 8 * lg);
            float m0 = masks[r9 + l15];
            float m1 = masks[r9 + 16 + l15];
            gru32_body(wFrag, bias, x9_0, x9_1, m0, m1, h_lds, lane, w,
                [&](int rt, int uu, uint2 pk) {
                    int row = rt * 16 + l15;
                    *(uint2*)(&h2_lds[row * LDH + half * 128 + uu]) = pk;
                });
        }
        __syncthreads();   // d9 reads of h_lds done; h2 half visible
    }

    // ---- d8 tile: x8 + h2_lds -> global lvl8 ----
    {
        const size_t r8 = (size_t)(255 + n) * B + (size_t)q * 32;
        bf16x8 x8_0 = load_xfrag(targets + (r8 + l15) * V + 8 * lg);
        bf16x8 x8_1 = load_xfrag(targets + (r8 + 16 + l15) * V + 8 * lg);
        float m0 = masks[r8 + l15];
        float m1 = masks[r8 + 16 + l15];
        gru32_body(wFrag, bias, x8_0, x8_1, m0, m1, h2_lds, lane, w,
            [&](int rt, int uu, uint2 pk) {
                int row = rt * 16 + l15;
                *(uint2*)(lvl8 + ((size_t)n * B + (size_t)q * 32 + row) * H + uu) = pk;
            });
    }
}

// ---------------------------------------------------------------------------
// tail4: 4 tree levels dtop..dtop-3 of one (subtree root pr, 16-row chunk c8)
// chained through LDS. Grid = (1 << (dtop-3)) * 8. 512 thr, 8-wave unit split.
// ---------------------------------------------------------------------------
__global__ __launch_bounds__(NT, 2) void tail4_kernel(
    const float* __restrict__ targets, const float* __restrict__ masks,
    const unsigned short* __restrict__ prev,     // level dtop+1 buffer
    unsigned short* __restrict__ outg,           // level dtop-3 buffer or null
    int s3, int s2, int s1, int s0,
    const unsigned short* __restrict__ wFrag, const float* __restrict__ bias,
    int do_proj, const unsigned short* __restrict__ pFrag, float* __restrict__ proj_out)
{
    __shared__ __attribute__((aligned(16))) unsigned short hc[32 * LDH];       // staging / proj input
    __shared__ __attribute__((aligned(16))) unsigned short h6[2 * 32 * LDH];   // dtop outputs
    __shared__ __attribute__((aligned(16))) unsigned short h5[32 * LDH];       // dtop-1 outputs
    __shared__ __attribute__((aligned(16))) unsigned short h4[16 * LDH];       // dtop-2 outputs

    const int tid = threadIdx.x;
    const int lane = tid & 63;
    const int w = tid >> 6;
    const int l15 = lane & 15;
    const int lg = lane >> 4;
    const int u0 = w * 16 + lg * 4;
    const int pr = blockIdx.x >> 3;
    const int c8 = blockIdx.x & 7;

    // ---- Phase 1: 4 x (stage from prev -> dtop M=32 tile -> h6) ----
    for (int s = 0; s < 4; ++s) {
        const int l1 = 4 * pr + s;   // node at level dtop-1
        #pragma unroll
        for (int t = 0; t < 2; ++t) {
            int task = t * NT + tid;
            int row = task >> 5;
            int ck = task & 31;
            int g = 4 * l1 + 2 * (row >> 4) + (ck >> 4);
            int4 v = *(const int4*)(prev + (((size_t)g) * B + (size_t)c8 * 16 + (row & 15)) * H + (ck & 15) * 8);
            *(int4*)(&hc[row * LDH + ck * 8]) = v;
        }
        size_t xr0 = ((size_t)(s3 + 2 * l1)) * B + (size_t)c8 * 16 + l15;
        size_t xr1 = ((size_t)(s3 + 2 * l1 + 1)) * B + (size_t)c8 * 16 + l15;
        bf16x8 xc0 = load_xfrag(targets + xr0 * V + 8 * lg);
        bf16x8 xc1 = load_xfrag(targets + xr1 * V + 8 * lg);
        float m0 = masks[xr0];
        float m1 = masks[xr1];
        __syncthreads();
        unsigned short* hout = h6 + (size_t)(s >> 1) * 32 * LDH;
        int rowbase = 16 * (s & 1);
        gru32_body(wFrag, bias, xc0, xc1, m0, m1, hc, lane, w,
            [&](int rt, int uu, uint2 pk) {
                *(uint2*)(&hout[(rowbase + l15) * LDH + rt * 128 + uu]) = pk;
            });
        __syncthreads();
    }

    // ---- Phase 2: 2 x (dtop-1 M=32 tile: h6[k] -> h5) ----
    for (int k = 0; k < 2; ++k) {
        int n1 = 4 * pr + 2 * k;
        size_t xr0 = ((size_t)(s2 + n1)) * B + (size_t)c8 * 16 + l15;
        size_t xr1 = ((size_t)(s2 + n1 + 1)) * B + (size_t)c8 * 16 + l15;
        bf16x8 xc0 = load_xfrag(targets + xr0 * V + 8 * lg);
        bf16x8 xc1 = load_xfrag(targets + xr1 * V + 8 * lg);
        float m0 = masks[xr0];
        float m1 = masks[xr1];
        const unsigned short* hin = h6 + (size_t)k * 32 * LDH;
        int rowbase = 16 * k;
        gru32_body(wFrag, bias, xc0, xc1, m0, m1, hin, lane, w,
            [&](int rt, int uu, uint2 pk) {
                *(uint2*)(&h5[(rowbase + l15) * LDH + rt * 128 + uu]) = pk;
            });
    }
    __syncthreads();

    // ---- Phase 3: dtop-2 M=32 tile: h5 -> h4 ----
    {
        size_t xr0 = ((size_t)(s1 + 2 * pr)) * B + (size_t)c8 * 16 + l15;
        size_t xr1 = ((size_t)(s1 + 2 * pr + 1)) * B + (size_t)c8 * 16 + l15;
        bf16x8 xc0 = load_xfrag(targets + xr0 * V + 8 * lg);
        bf16x8 xc1 = load_xfrag(targets + xr1 * V + 8 * lg);
        float m0 = masks[xr0];
        float m1 = masks[xr1];
        gru32_body(wFrag, bias, xc0, xc1, m0, m1, h5, lane, w,
            [&](int rt, int uu, uint2 pk) {
                *(uint2*)(&h4[l15 * LDH + rt * 128 + uu]) = pk;
            });
    }
    __syncthreads();

    // ---- Phase 4: dtop-3 M=16 tile: h4 -> outg / proj input ----
    {
        size_t xrp = ((size_t)(s0 + pr)) * B + (size_t)c8 * 16 + l15;
        bf16x8 xp = load_xfrag(targets + xrp * V + 8 * lg);
        float m = masks[xrp];
        f32x4 acc_r = *(const f32x4*)(bias + u0);
        f32x4 acc_z = *(const f32x4*)(bias + 128 + u0);
        f32x4 acc_i = *(const f32x4*)(bias + 256 + u0);
        f32x4 acc_h = *(const f32x4*)(bias + 384 + u0);
        {
            bf16x8 wr_ = *(const bf16x8*)(wFrag + ((size_t)(w) * 64 + lane) * 8);
            bf16x8 wz_ = *(const bf16x8*)(wFrag + ((size_t)(8 + w) * 64 + lane) * 8);
            bf16x8 wn_ = *(const bf16x8*)(wFrag + ((size_t)(16 + w) * 64 + lane) * 8);
            acc_r = mfma_wx(wr_, xp, acc_r);
            acc_z = mfma_wx(wz_, xp, acc_z);
            acc_i = mfma_wx(wn_, xp, acc_i);
        }
        #pragma unroll 2
        for (int ks = 1; ks <= 8; ++ks) {
            bf16x8 a = *(const bf16x8*)(&h4[l15 * LDH + (ks - 1) * 32 + 8 * lg]);
            size_t fb = (size_t)ks * 24 * 64;
            bf16x8 wr_ = *(const bf16x8*)(wFrag + (fb + (size_t)(w) * 64 + lane) * 8);
            bf16x8 wz_ = *(const bf16x8*)(wFrag + (fb + (size_t)(8 + w) * 64 + lane) * 8);
            bf16x8 wn_ = *(const bf16x8*)(wFrag + (fb + (size_t)(16 + w) * 64 + lane) * 8);
            acc_r = mfma_wx(wr_, a, acc_r);
            acc_z = mfma_wx(wz_, a, acc_z);
            acc_h = mfma_wx(wn_, a, acc_h);
        }
        ushort4 h1v = *(const ushort4*)(&h4[l15 * LDH + u0]);
        ushort4 h2v = *(const ushort4*)(&h4[l15 * LDH + 128 + u0]);
        const unsigned short* h1p = (const unsigned short*)&h1v;
        const unsigned short* h2p = (const unsigned short*)&h2v;
        float ho[4];
        #pragma unroll
        for (int reg = 0; reg < 4; ++reg) {
            float rg = sig_pre(acc_r[reg]);
            float zg = sig_pre(acc_z[reg]);
            float cg = tanh_pre(acc_i[reg] + rg * acc_h[reg]);
            float hm = 0.5f * bf2f(h1p[reg]) + 0.5f * bf2f(h2p[reg]);
            ho[reg] = (cg + zg * (hm - cg)) * m;
        }
        uint2 pk = pack4(ho[0], ho[1], ho[2], ho[3]);
        if (outg)
            *(uint2*)(outg + ((size_t)pr * B + (size_t)c8 * 16 + l15) * H + u0) = pk;
        if (do_proj)
            *(uint2*)(&hc[l15 * LDH + u0]) = pk;   // hc is dead; race-free proj input
    }

    if (do_proj) {
        __syncthreads();
        f32x4 pa[2];
        #pragma unroll
        for (int jj = 0; jj < 2; ++jj) {
            int ct2 = 2 * w + jj;
            int sel = ct2 >> 3, tl = ct2 & 7;
            pa[jj] = *(const f32x4*)(bias + 512 + sel * 128 + tl * 16 + lg * 4);
        }
        #pragma unroll
        for (int ks = 0; ks < 4; ++ks) {
            bf16x8 a = *(const bf16x8*)(&hc[l15 * LDH + ks * 32 + 8 * lg]);
            #pragma unroll
            for (int jj = 0; jj < 2; ++jj) {
                bf16x8 f = *(const bf16x8*)(pFrag + (((size_t)ks * 16 + 2 * w + jj) * 64 + lane) * 8);
                pa[jj] = mfma_wx(f, a, pa[jj]);
            }
        }
        #pragma unroll
        for (int jj = 0; jj < 2; ++jj) {
            int ct2 = 2 * w + jj;
            int sel = ct2 >> 3, tl = ct2 & 7;
            int up = tl * 16 + lg * 4;
            int row = c8 * 16 + l15;
            *(f32x4*)(proj_out + ((size_t)sel * B + row) * H + up) = pa[jj];
        }
    }
}

// ---------------------------------------------------------------------------
extern "C" void kernel_launch(void* const* d_in, const int* in_sizes, int n_in,
                              void* d_out, int out_size, void* d_ws, size_t ws_size,
                              hipStream_t stream)
{
    const float* targets = (const float*)d_in[0];
    const float* masks   = (const float*)d_in[1];
    const float* wir_w = (const float*)d_in[2];  const float* wir_b = (const float*)d_in[3];
    const float* whr_w = (const float*)d_in[4];  const float* whr_b = (const float*)d_in[5];
    const float* wiz_w = (const float*)d_in[6];  const float* wiz_b = (const float*)d_in[7];
    const float* whz_w = (const float*)d_in[8];  const float* whz_b = (const float*)d_in[9];
    const float* win_w = (const float*)d_in[10]; const float* win_b = (const float*)d_in[11];
    const float* whn_w = (const float*)d_in[12]; const float* whn_b = (const float*)d_in[13];
    const float* mu_w  = (const float*)d_in[14]; const float* mu_b  = (const float*)d_in[15];
    const float* lv_w  = (const float*)d_in[16]; const float* lv_b  = (const float*)d_in[17];

    unsigned short* ws16 = (unsigned short*)d_ws;
    unsigned short* lvl8 = ws16;                               // 256*128*128
    unsigned short* lvl4 = lvl8 + (size_t)256 * B * H;         // 16*128*128
    unsigned short* wFrag = lvl4 + (size_t)16 * B * H;         // 110592 bf16
    unsigned short* pFrag = wFrag + 110592;                    // 32768 bf16
    float*          biasw = (float*)(pFrag + 32768);           // 768 fp32

    prep_pack<<<70, 256, 0, stream>>>(
        wir_w, whr_w, wiz_w, whz_w, win_w, whn_w,
        wir_b, whr_b, wiz_b, whz_b, win_b, whn_b,
        mu_w, mu_b, lv_w, lv_b, wFrag, pFrag, biasw);

    subtree8_kernel<<<1024, NT, 0, stream>>>(targets, masks, lvl8, wFrag, biasw);

    // levels 7..4 (lvl8 -> lvl4), only lvl4 materialized
    tail4_kernel<<<128, NT, 0, stream>>>(
        targets, masks, lvl8, lvl4, 127, 63, 31, 15,
        wFrag, biasw, 0, nullptr, nullptr);

    // levels 3..0 + fused projection (lvl4 -> d_out)
    tail4_kernel<<<8, NT, 0, stream>>>(
        targets, masks, lvl4, nullptr, 7, 3, 1, 0,
        wFrag, biasw, 1, pFrag, (float*)d_out);
}

// Round 14
// 115.616 us; speedup vs baseline: 1.3876x; 1.0912x over previous
//
#include <hip/hip_runtime.h>
#include <hip/hip_bf16.h>
#include <math.h>

#define B 128
#define V 32
#define H 128
#define LDH 264    // h-region row pitch in bf16 elems (528 B)
#define NT 512     // 8 waves; wave w owns units [w*16, w*16+16)

typedef __attribute__((ext_vector_type(8))) short bf16x8;
typedef __attribute__((ext_vector_type(4))) float f32x4;

// Swapped-operand layout: D = W_frag x Act_frag; lane owns batch row (lane&15)
// and 4 consecutive units ((lane>>4)*4 + reg).
__device__ inline f32x4 mfma_wx(bf16x8 wf, bf16x8 xf, f32x4 c) {
    return __builtin_amdgcn_mfma_f32_16x16x32_bf16(wf, xf, c, 0, 0, 0);
}
__device__ inline unsigned short f2bf(float f) {
    __hip_bfloat16 h = __float2bfloat16(f);
    return __builtin_bit_cast(unsigned short, h);
}
__device__ inline float bf2f(unsigned short u) {
    unsigned int x = ((unsigned int)u) << 16;
    return __builtin_bit_cast(float, x);
}
// pre-scaled activations: weights/biases for r,z carry -1/ln2, n carries 2/ln2
__device__ inline float sig_pre(float y)  { return __builtin_amdgcn_rcpf(1.f + __builtin_amdgcn_exp2f(y)); }
__device__ inline float tanh_pre(float y) { return 1.f - 2.f * __builtin_amdgcn_rcpf(__builtin_amdgcn_exp2f(y) + 1.f); }
__device__ inline bf16x8 load_xfrag(const float* p) {
    float4 a = *(const float4*)p;
    float4 b = *(const float4*)(p + 4);
    bf16x8 r;
    r[0] = (short)f2bf(a.x); r[1] = (short)f2bf(a.y);
    r[2] = (short)f2bf(a.z); r[3] = (short)f2bf(a.w);
    r[4] = (short)f2bf(b.x); r[5] = (short)f2bf(b.y);
    r[6] = (short)f2bf(b.z); r[7] = (short)f2bf(b.w);
    return r;
}
__device__ inline uint2 pack4(float a, float b, float c, float d) {
    uint2 r;
    r.x = (unsigned int)f2bf(a) | ((unsigned int)f2bf(b) << 16);
    r.y = (unsigned int)f2bf(c) | ((unsigned int)f2bf(d) << 16);
    return r;
}

// ---------------------------------------------------------------------------
// Pack GRU weights (PRE-SCALED) + proj weights into MFMA fragment order.
// ---------------------------------------------------------------------------
__global__ void prep_pack(const float* __restrict__ wir_w, const float* __restrict__ whr_w,
                          const float* __restrict__ wiz_w, const float* __restrict__ whz_w,
                          const float* __restrict__ win_w, const float* __restrict__ whn_w,
                          const float* __restrict__ wir_b, const float* __restrict__ whr_b,
                          const float* __restrict__ wiz_b, const float* __restrict__ whz_b,
                          const float* __restrict__ win_b, const float* __restrict__ whn_b,
                          const float* __restrict__ mu_w, const float* __restrict__ mu_b,
                          const float* __restrict__ lv_w, const float* __restrict__ lv_b,
                          unsigned short* __restrict__ wFrag, unsigned short* __restrict__ pFrag,
                          float* __restrict__ bias)
{
    int idx = blockIdx.x * blockDim.x + threadIdx.x;
    if (idx < 13824) {
        int lane = idx & 63;
        int ctks = idx >> 6;
        int ct = ctks % 24;
        int ks = ctks / 24;
        int g = ct >> 3;
        int t = ct & 7;
        int u = t * 16 + (lane & 15);
        const float scl = (g == 2) ? 2.88539008f : -1.44269504f;
        const float* wi = (g == 0) ? wir_w : (g == 1) ? wiz_w : win_w;
        const float* wh = (g == 0) ? whr_w : (g == 1) ? whz_w : whn_w;
        unsigned short v[8] __attribute__((aligned(16)));
        #pragma unroll
        for (int i = 0; i < 8; ++i) {
            float f;
            if (ks == 0) { int k = 8 * (lane >> 4) + i; f = wi[u * V + k]; }
            else         { int k = (ks - 1) * 32 + 8 * (lane >> 4) + i; f = wh[u * 256 + k]; }
            v[i] = f2bf(f * scl);
        }
        *(int4*)(wFrag + (size_t)idx * 8) = *(const int4*)v;
    } else if (idx < 13824 + 4096) {
        int pidx = idx - 13824;
        int lane = pidx & 63;
        int rest = pidx >> 6;
        int ct2 = rest & 15;
        int ks = rest >> 4;
        int sel = ct2 >> 3, tl = ct2 & 7;
        int u = tl * 16 + (lane & 15);
        const float* wsrc = sel ? lv_w : mu_w;
        unsigned short v[8] __attribute__((aligned(16)));
        #pragma unroll
        for (int i = 0; i < 8; ++i) {
            int k = ks * 32 + 8 * (lane >> 4) + i;
            v[i] = f2bf(wsrc[u * H + k]);
        }
        *(int4*)(pFrag + (size_t)pidx * 8) = *(const int4*)v;
    }
    if (idx < 6 * H) {
        int s = idx / H, u = idx % H;
        float val;
        if (s == 0)      val = (wir_b[u] + whr_b[u]) * -1.44269504f;
        else if (s == 1) val = (wiz_b[u] + whz_b[u]) * -1.44269504f;
        else if (s == 2) val = win_b[u] * 2.88539008f;
        else if (s == 3) val = whn_b[u] * 2.88539008f;
        else if (s == 4) val = mu_b[u];
        else             val = lv_b[u];
        bias[idx] = val;
    }
}

// ---------------------------------------------------------------------------
// Load this wave's 27 weight frags into registers (once per kernel).
// ---------------------------------------------------------------------------
__device__ __forceinline__ void load_wreg(
    const unsigned short* __restrict__ wFrag, int lane, int w,
    bf16x8 (&wr)[9], bf16x8 (&wz)[9], bf16x8 (&wn)[9])
{
    #pragma unroll
    for (int ks = 0; ks < 9; ++ks) {
        size_t fb = (size_t)ks * 24 * 64;
        wr[ks] = *(const bf16x8*)(wFrag + (fb + (size_t)(w) * 64 + lane) * 8);
        wz[ks] = *(const bf16x8*)(wFrag + (fb + (size_t)(8 + w) * 64 + lane) * 8);
        wn[ks] = *(const bf16x8*)(wFrag + (fb + (size_t)(16 + w) * 64 + lane) * 8);
    }
}

// ---------------------------------------------------------------------------
// M=32 GRU tile body, weights-stationary. K0 from x frags, K1..8 from hin.
// Per wave: 8 f32x4 acc. Epilogue hands each 4-unit pack to `emit`.
// ---------------------------------------------------------------------------
template <typename EMIT>
__device__ __forceinline__ void gru32_ws(
    const bf16x8 (&wr)[9], const bf16x8 (&wz)[9], const bf16x8 (&wn)[9],
    const float* __restrict__ bias,
    bf16x8 x0, bf16x8 x1, float m0, float m1,
    const unsigned short* __restrict__ hin,
    int lane, int w, EMIT emit)
{
    const int l15 = lane & 15;
    const int lg = lane >> 4;
    const int u0 = w * 16 + lg * 4;

    f32x4 acc_r[2], acc_z[2], acc_i[2], acc_h[2];
    {
        f32x4 b0 = *(const f32x4*)(bias + u0);
        f32x4 b1 = *(const f32x4*)(bias + 128 + u0);
        f32x4 b2 = *(const f32x4*)(bias + 256 + u0);
        f32x4 b3 = *(const f32x4*)(bias + 384 + u0);
        acc_r[0] = b0; acc_r[1] = b0;
        acc_z[0] = b1; acc_z[1] = b1;
        acc_i[0] = b2; acc_i[1] = b2;
        acc_h[0] = b3; acc_h[1] = b3;
    }
    acc_r[0] = mfma_wx(wr[0], x0, acc_r[0]);
    acc_r[1] = mfma_wx(wr[0], x1, acc_r[1]);
    acc_z[0] = mfma_wx(wz[0], x0, acc_z[0]);
    acc_z[1] = mfma_wx(wz[0], x1, acc_z[1]);
    acc_i[0] = mfma_wx(wn[0], x0, acc_i[0]);
    acc_i[1] = mfma_wx(wn[0], x1, acc_i[1]);
    #pragma unroll
    for (int ks = 1; ks <= 8; ++ks) {
        bf16x8 a0 = *(const bf16x8*)(&hin[l15 * LDH + (ks - 1) * 32 + 8 * lg]);
        bf16x8 a1 = *(const bf16x8*)(&hin[(16 + l15) * LDH + (ks - 1) * 32 + 8 * lg]);
        acc_r[0] = mfma_wx(wr[ks], a0, acc_r[0]);
        acc_r[1] = mfma_wx(wr[ks], a1, acc_r[1]);
        acc_z[0] = mfma_wx(wz[ks], a0, acc_z[0]);
        acc_z[1] = mfma_wx(wz[ks], a1, acc_z[1]);
        acc_h[0] = mfma_wx(wn[ks], a0, acc_h[0]);
        acc_h[1] = mfma_wx(wn[ks], a1, acc_h[1]);
    }
    #pragma unroll
    for (int rt = 0; rt < 2; ++rt) {
        float m = rt ? m1 : m0;
        int hrow = rt * 16 + l15;
        ushort4 h1v = *(const ushort4*)(&hin[hrow * LDH + u0]);
        ushort4 h2v = *(const ushort4*)(&hin[hrow * LDH + 128 + u0]);
        const unsigned short* h1p = (const unsigned short*)&h1v;
        const unsigned short* h2p = (const unsigned short*)&h2v;
        float ho[4];
        #pragma unroll
        for (int reg = 0; reg < 4; ++reg) {
            float rg = sig_pre(acc_r[rt][reg]);
            float zg = sig_pre(acc_z[rt][reg]);
            float cg = tanh_pre(acc_i[rt][reg] + rg * acc_h[rt][reg]);
            float hm = 0.5f * bf2f(h1p[reg]) + 0.5f * bf2f(h2p[reg]);
            ho[reg] = (cg + zg * (hm - cg)) * m;
        }
        emit(rt, u0, pack4(ho[0], ho[1], ho[2], ho[3]));
    }
}

// ---------------------------------------------------------------------------
// Fused subtree kernel v5: levels leaf+9+8, 512 thr, weights-stationary.
// Grid 1024: block (n = d8 node, q = 32-row chunk). lvl9 never touches HBM.
// ---------------------------------------------------------------------------
__global__ __launch_bounds__(NT, 2) void subtree8_kernel(
    const float* __restrict__ targets, const float* __restrict__ masks,
    unsigned short* __restrict__ lvl8,
    const unsigned short* __restrict__ wFrag, const float* __restrict__ bias)
{
    __shared__ __attribute__((aligned(16))) unsigned short h_lds[32 * LDH];
    __shared__ __attribute__((aligned(16))) unsigned short h2_lds[32 * LDH];

    const int tid = threadIdx.x;
    const int lane = tid & 63;
    const int w = tid >> 6;
    const int l15 = lane & 15;
    const int lg = lane >> 4;
    const int u0 = w * 16 + lg * 4;
    const int n = blockIdx.x >> 2;
    const int q = blockIdx.x & 3;

    bf16x8 wr[9], wz[9], wn[9];
    load_wreg(wFrag, lane, w, wr, wz, wn);

    for (int half = 0; half < 2; ++half) {
        const int j = 2 * n + half;
        const size_t r9 = (size_t)(511 + j) * B + (size_t)q * 32;

        // ---- leaf children of j -> h_lds (K0 only; h1=h2=0) ----
        #pragma unroll
        for (int c = 0; c < 2; ++c) {
            const size_t crow = (size_t)(1023 + 2 * j + c) * B + (size_t)q * 32;
            bf16x8 xf0 = load_xfrag(targets + (crow + l15) * V + 8 * lg);
            bf16x8 xf1 = load_xfrag(targets + (crow + 16 + l15) * V + 8 * lg);
            float m0 = masks[crow + l15];
            float m1 = masks[crow + 16 + l15];
            f32x4 ar[2], az[2], an[2], bh;
            {
                f32x4 b0 = *(const f32x4*)(bias + u0);
                f32x4 b1 = *(const f32x4*)(bias + 128 + u0);
                f32x4 b2 = *(const f32x4*)(bias + 256 + u0);
                bh       = *(const f32x4*)(bias + 384 + u0);
                ar[0] = b0; ar[1] = b0;
                az[0] = b1; az[1] = b1;
                an[0] = b2; an[1] = b2;
            }
            ar[0] = mfma_wx(wr[0], xf0, ar[0]);
            ar[1] = mfma_wx(wr[0], xf1, ar[1]);
            az[0] = mfma_wx(wz[0], xf0, az[0]);
            az[1] = mfma_wx(wz[0], xf1, az[1]);
            an[0] = mfma_wx(wn[0], xf0, an[0]);
            an[1] = mfma_wx(wn[0], xf1, an[1]);
            #pragma unroll
            for (int rt = 0; rt < 2; ++rt) {
                float m = rt ? m1 : m0;
                int row = rt * 16 + l15;
                float ho[4];
                #pragma unroll
                for (int reg = 0; reg < 4; ++reg) {
                    float rg = sig_pre(ar[rt][reg]);
                    float zg = sig_pre(az[rt][reg]);
                    float cg = tanh_pre(an[rt][reg] + rg * bh[reg]);
                    ho[reg] = (cg - zg * cg) * m;
                }
                *(uint2*)(&h_lds[row * LDH + c * 128 + u0]) = pack4(ho[0], ho[1], ho[2], ho[3]);
            }
        }
        __syncthreads();   // h_lds (leaf h) ready

        // ---- d9 tile: out -> h2_lds ----
        {
            bf16x8 x9_0 = load_xfrag(targets + (r9 + l15) * V + 8 * lg);
            bf16x8 x9_1 = load_xfrag(targets + (r9 + 16 + l15) * V + 8 * lg);
            float m0 = masks[r9 + l15];
            float m1 = masks[r9 + 16 + l15];
            gru32_ws(wr, wz, wn, bias, x9_0, x9_1, m0, m1, h_lds, lane, w,
                [&](int rt, int uu, uint2 pk) {
                    int row = rt * 16 + l15;
                    *(uint2*)(&h2_lds[row * LDH + half * 128 + uu]) = pk;
                });
        }
        __syncthreads();   // d9 reads of h_lds done; h2 half visible
    }

    // ---- d8 tile: x8 + h2_lds -> global lvl8 ----
    {
        const size_t r8 = (size_t)(255 + n) * B + (size_t)q * 32;
        bf16x8 x8_0 = load_xfrag(targets + (r8 + l15) * V + 8 * lg);
        bf16x8 x8_1 = load_xfrag(targets + (r8 + 16 + l15) * V + 8 * lg);
        float m0 = masks[r8 + l15];
        float m1 = masks[r8 + 16 + l15];
        gru32_ws(wr, wz, wn, bias, x8_0, x8_1, m0, m1, h2_lds, lane, w,
            [&](int rt, int uu, uint2 pk) {
                int row = rt * 16 + l15;
                *(uint2*)(lvl8 + ((size_t)n * B + (size_t)q * 32 + row) * H + uu) = pk;
            });
    }
}

// ---------------------------------------------------------------------------
// tail4: 4 tree levels dtop..dtop-3 of one (subtree root pr, 16-row chunk c8)
// chained through LDS, weights-stationary. Grid = (1 << (dtop-3)) * 8.
// ---------------------------------------------------------------------------
__global__ __launch_bounds__(NT, 2) void tail4_kernel(
    const float* __restrict__ targets, const float* __restrict__ masks,
    const unsigned short* __restrict__ prev,     // level dtop+1 buffer
    unsigned short* __restrict__ outg,           // level dtop-3 buffer or null
    int s3, int s2, int s1, int s0,
    const unsigned short* __restrict__ wFrag, const float* __restrict__ bias,
    int do_proj, const unsigned short* __restrict__ pFrag, float* __restrict__ proj_out)
{
    __shared__ __attribute__((aligned(16))) unsigned short hc[32 * LDH];       // staging / proj input
    __shared__ __attribute__((aligned(16))) unsigned short h6[2 * 32 * LDH];   // dtop outputs
    __shared__ __attribute__((aligned(16))) unsigned short h5[32 * LDH];       // dtop-1 outputs
    __shared__ __attribute__((aligned(16))) unsigned short h4[16 * LDH];       // dtop-2 outputs

    const int tid = threadIdx.x;
    const int lane = tid & 63;
    const int w = tid >> 6;
    const int l15 = lane & 15;
    const int lg = lane >> 4;
    const int u0 = w * 16 + lg * 4;
    const int pr = blockIdx.x >> 3;
    const int c8 = blockIdx.x & 7;

    bf16x8 wr[9], wz[9], wn[9];
    load_wreg(wFrag, lane, w, wr, wz, wn);

    // ---- Phase 1: 4 x (stage from prev -> dtop M=32 tile -> h6) ----
    for (int s = 0; s < 4; ++s) {
        const int l1 = 4 * pr + s;   // node at level dtop-1
        #pragma unroll
        for (int t = 0; t < 2; ++t) {
            int task = t * NT + tid;
            int row = task >> 5;
            int ck = task & 31;
            int g = 4 * l1 + 2 * (row >> 4) + (ck >> 4);
            int4 v = *(const int4*)(prev + (((size_t)g) * B + (size_t)c8 * 16 + (row & 15)) * H + (ck & 15) * 8);
            *(int4*)(&hc[row * LDH + ck * 8]) = v;
        }
        size_t xr0 = ((size_t)(s3 + 2 * l1)) * B + (size_t)c8 * 16 + l15;
        size_t xr1 = ((size_t)(s3 + 2 * l1 + 1)) * B + (size_t)c8 * 16 + l15;
        bf16x8 xc0 = load_xfrag(targets + xr0 * V + 8 * lg);
        bf16x8 xc1 = load_xfrag(targets + xr1 * V + 8 * lg);
        float m0 = masks[xr0];
        float m1 = masks[xr1];
        __syncthreads();
        unsigned short* hout = h6 + (size_t)(s >> 1) * 32 * LDH;
        int rowbase = 16 * (s & 1);
        gru32_ws(wr, wz, wn, bias, xc0, xc1, m0, m1, hc, lane, w,
            [&](int rt, int uu, uint2 pk) {
                *(uint2*)(&hout[(rowbase + l15) * LDH + rt * 128 + uu]) = pk;
            });
        __syncthreads();
    }

    // ---- Phase 2: 2 x (dtop-1 M=32 tile: h6[k] -> h5) ----
    for (int k = 0; k < 2; ++k) {
        int n1 = 4 * pr + 2 * k;
        size_t xr0 = ((size_t)(s2 + n1)) * B + (size_t)c8 * 16 + l15;
        size_t xr1 = ((size_t)(s2 + n1 + 1)) * B + (size_t)c8 * 16 + l15;
        bf16x8 xc0 = load_xfrag(targets + xr0 * V + 8 * lg);
        bf16x8 xc1 = load_xfrag(targets + xr1 * V + 8 * lg);
        float m0 = masks[xr0];
        float m1 = masks[xr1];
        const unsigned short* hin = h6 + (size_t)k * 32 * LDH;
        int rowbase = 16 * k;
        gru32_ws(wr, wz, wn, bias, xc0, xc1, m0, m1, hin, lane, w,
            [&](int rt, int uu, uint2 pk) {
                *(uint2*)(&h5[(rowbase + l15) * LDH + rt * 128 + uu]) = pk;
            });
    }
    __syncthreads();

    // ---- Phase 3: dtop-2 M=32 tile: h5 -> h4 ----
    {
        size_t xr0 = ((size_t)(s1 + 2 * pr)) * B + (size_t)c8 * 16 + l15;
        size_t xr1 = ((size_t)(s1 + 2 * pr + 1)) * B + (size_t)c8 * 16 + l15;
        bf16x8 xc0 = load_xfrag(targets + xr0 * V + 8 * lg);
        bf16x8 xc1 = load_xfrag(targets + xr1 * V + 8 * lg);
        float m0 = masks[xr0];
        float m1 = masks[xr1];
        gru32_ws(wr, wz, wn, bias, xc0, xc1, m0, m1, h5, lane, w,
            [&](int rt, int uu, uint2 pk) {
                *(uint2*)(&h4[l15 * LDH + rt * 128 + uu]) = pk;
            });
    }
    __syncthreads();

    // ---- Phase 4: dtop-3 M=16 tile: h4 -> outg / proj input ----
    {
        size_t xrp = ((size_t)(s0 + pr)) * B + (size_t)c8 * 16 + l15;
        bf16x8 xp = load_xfrag(targets + xrp * V + 8 * lg);
        float m = masks[xrp];
        f32x4 acc_r = *(const f32x4*)(bias + u0);
        f32x4 acc_z = *(const f32x4*)(bias + 128 + u0);
        f32x4 acc_i = *(const f32x4*)(bias + 256 + u0);
        f32x4 acc_h = *(const f32x4*)(bias + 384 + u0);
        acc_r = mfma_wx(wr[0], xp, acc_r);
        acc_z = mfma_wx(wz[0], xp, acc_z);
        acc_i = mfma_wx(wn[0], xp, acc_i);
        #pragma unroll
        for (int ks = 1; ks <= 8; ++ks) {
            bf16x8 a = *(const bf16x8*)(&h4[l15 * LDH + (ks - 1) * 32 + 8 * lg]);
            acc_r = mfma_wx(wr[ks], a, acc_r);
            acc_z = mfma_wx(wz[ks], a, acc_z);
            acc_h = mfma_wx(wn[ks], a, acc_h);
        }
        ushort4 h1v = *(const ushort4*)(&h4[l15 * LDH + u0]);
        ushort4 h2v = *(const ushort4*)(&h4[l15 * LDH + 128 + u0]);
        const unsigned short* h1p = (const unsigned short*)&h1v;
        const unsigned short* h2p = (const unsigned short*)&h2v;
        float ho[4];
        #pragma unroll
        for (int reg = 0; reg < 4; ++reg) {
            float rg = sig_pre(acc_r[reg]);
            float zg = sig_pre(acc_z[reg]);
            float cg = tanh_pre(acc_i[reg] + rg * acc_h[reg]);
            float hm = 0.5f * bf2f(h1p[reg]) + 0.5f * bf2f(h2p[reg]);
            ho[reg] = (cg + zg * (hm - cg)) * m;
        }
        uint2 pk = pack4(ho[0], ho[1], ho[2], ho[3]);
        if (outg)
            *(uint2*)(outg + ((size_t)pr * B + (size_t)c8 * 16 + l15) * H + u0) = pk;
        if (do_proj)
            *(uint2*)(&hc[l15 * LDH + u0]) = pk;   // hc is dead; race-free proj input
    }

    if (do_proj) {
        __syncthreads();
        f32x4 pa[2];
        #pragma unroll
        for (int jj = 0; jj < 2; ++jj) {
            int ct2 = 2 * w + jj;
            int sel = ct2 >> 3, tl = ct2 & 7;
            pa[jj] = *(const f32x4*)(bias + 512 + sel * 128 + tl * 16 + lg * 4);
        }
        #pragma unroll
        for (int ks = 0; ks < 4; ++ks) {
            bf16x8 a = *(const bf16x8*)(&hc[l15 * LDH + ks * 32 + 8 * lg]);
            #pragma unroll
            for (int jj = 0; jj < 2; ++jj) {
                bf16x8 f = *(const bf16x8*)(pFrag + (((size_t)ks * 16 + 2 * w + jj) * 64 + lane) * 8);
                pa[jj] = mfma_wx(f, a, pa[jj]);
            }
        }
        #pragma unroll
        for (int jj = 0; jj < 2; ++jj) {
            int ct2 = 2 * w + jj;
            int sel = ct2 >> 3, tl = ct2 & 7;
            int up = tl * 16 + lg * 4;
            int row = c8 * 16 + l15;
            *(f32x4*)(proj_out + ((size_t)sel * B + row) * H + up) = pa[jj];
        }
    }
}

// ---------------------------------------------------------------------------
extern "C" void kernel_launch(void* const* d_in, const int* in_sizes, int n_in,
                              void* d_out, int out_size, void* d_ws, size_t ws_size,
                              hipStream_t stream)
{
    const float* targets = (const float*)d_in[0];
    const float* masks   = (const float*)d_in[1];
    const float* wir_w = (const float*)d_in[2];  const float* wir_b = (const float*)d_in[3];
    const float* whr_w = (const float*)d_in[4];  const float* whr_b = (const float*)d_in[5];
    const float* wiz_w = (const float*)d_in[6];  const float* wiz_b = (const float*)d_in[7];
    const float* whz_w = (const float*)d_in[8];  const float* whz_b = (const float*)d_in[9];
    const float* win_w = (const float*)d_in[10]; const float* win_b = (const float*)d_in[11];
    const float* whn_w = (const float*)d_in[12]; const float* whn_b = (const float*)d_in[13];
    const float* mu_w  = (const float*)d_in[14]; const float* mu_b  = (const float*)d_in[15];
    const float* lv_w  = (const float*)d_in[16]; const float* lv_b  = (const float*)d_in[17];

    unsigned short* ws16 = (unsigned short*)d_ws;
    unsigned short* lvl8 = ws16;                               // 256*128*128
    unsigned short* lvl4 = lvl8 + (size_t)256 * B * H;         // 16*128*128
    unsigned short* wFrag = lvl4 + (size_t)16 * B * H;         // 110592 bf16
    unsigned short* pFrag = wFrag + 110592;                    // 32768 bf16
    float*          biasw = (float*)(pFrag + 32768);           // 768 fp32

    prep_pack<<<70, 256, 0, stream>>>(
        wir_w, whr_w, wiz_w, whz_w, win_w, whn_w,
        wir_b, whr_b, wiz_b, whz_b, win_b, whn_b,
        mu_w, mu_b, lv_w, lv_b, wFrag, pFrag, biasw);

    subtree8_kernel<<<1024, NT, 0, stream>>>(targets, masks, lvl8, wFrag, biasw);

    // levels 7..4 (lvl8 -> lvl4), only lvl4 materialized
    tail4_kernel<<<128, NT, 0, stream>>>(
        targets, masks, lvl8, lvl4, 127, 63, 31, 15,
        wFrag, biasw, 0, nullptr, nullptr);

    // levels 3..0 + fused projection (lvl4 -> d_out)
    tail4_kernel<<<8, NT, 0, stream>>>(
        targets, masks, lvl4, nullptr, 7, 3, 1, 0,
        wFrag, biasw, 1, pFrag, (float*)d_out);
}

// Round 15
// 110.201 us; speedup vs baseline: 1.4558x; 1.0491x over previous
//
#include <hip/hip_runtime.h>
#include <hip/hip_bf16.h>
#include <math.h>

#define B 128
#define V 32
#define H 128
#define LDH 264    // h-region row pitch in bf16 elems (528 B)
#define NT 512     // 8 waves; wave w owns units [w*16, w*16+16)

typedef __attribute__((ext_vector_type(8))) short bf16x8;
typedef __attribute__((ext_vector_type(4))) float f32x4;

// Swapped-operand layout: D = W_frag x Act_frag; lane owns batch row (lane&15)
// and 4 consecutive units ((lane>>4)*4 + reg).
__device__ inline f32x4 mfma_wx(bf16x8 wf, bf16x8 xf, f32x4 c) {
    return __builtin_amdgcn_mfma_f32_16x16x32_bf16(wf, xf, c, 0, 0, 0);
}
__device__ inline unsigned short f2bf(float f) {
    __hip_bfloat16 h = __float2bfloat16(f);
    return __builtin_bit_cast(unsigned short, h);
}
__device__ inline float bf2f(unsigned short u) {
    unsigned int x = ((unsigned int)u) << 16;
    return __builtin_bit_cast(float, x);
}
// pre-scaled activations: weights/biases for r,z carry -1/ln2, n carries 2/ln2
__device__ inline float sig_pre(float y)  { return __builtin_amdgcn_rcpf(1.f + __builtin_amdgcn_exp2f(y)); }
__device__ inline float tanh_pre(float y) { return 1.f - 2.f * __builtin_amdgcn_rcpf(__builtin_amdgcn_exp2f(y) + 1.f); }
__device__ inline bf16x8 load_xfrag(const float* p) {
    float4 a = *(const float4*)p;
    float4 b = *(const float4*)(p + 4);
    bf16x8 r;
    r[0] = (short)f2bf(a.x); r[1] = (short)f2bf(a.y);
    r[2] = (short)f2bf(a.z); r[3] = (short)f2bf(a.w);
    r[4] = (short)f2bf(b.x); r[5] = (short)f2bf(b.y);
    r[6] = (short)f2bf(b.z); r[7] = (short)f2bf(b.w);
    return r;
}
__device__ inline uint2 pack4(float a, float b, float c, float d) {
    uint2 r;
    r.x = (unsigned int)f2bf(a) | ((unsigned int)f2bf(b) << 16);
    r.y = (unsigned int)f2bf(c) | ((unsigned int)f2bf(d) << 16);
    return r;
}

// ---------------------------------------------------------------------------
// Pack GRU weights (PRE-SCALED) + proj weights into MFMA fragment order.
// ---------------------------------------------------------------------------
__global__ void prep_pack(const float* __restrict__ wir_w, const float* __restrict__ whr_w,
                          const float* __restrict__ wiz_w, const float* __restrict__ whz_w,
                          const float* __restrict__ win_w, const float* __restrict__ whn_w,
                          const float* __restrict__ wir_b, const float* __restrict__ whr_b,
                          const float* __restrict__ wiz_b, const float* __restrict__ whz_b,
                          const float* __restrict__ win_b, const float* __restrict__ whn_b,
                          const float* __restrict__ mu_w, const float* __restrict__ mu_b,
                          const float* __restrict__ lv_w, const float* __restrict__ lv_b,
                          unsigned short* __restrict__ wFrag, unsigned short* __restrict__ pFrag,
                          float* __restrict__ bias)
{
    int idx = blockIdx.x * blockDim.x + threadIdx.x;
    if (idx < 13824) {
        int lane = idx & 63;
        int ctks = idx >> 6;
        int ct = ctks % 24;
        int ks = ctks / 24;
        int g = ct >> 3;
        int t = ct & 7;
        int u = t * 16 + (lane & 15);
        const float scl = (g == 2) ? 2.88539008f : -1.44269504f;
        const float* wi = (g == 0) ? wir_w : (g == 1) ? wiz_w : win_w;
        const float* wh = (g == 0) ? whr_w : (g == 1) ? whz_w : whn_w;
        unsigned short v[8] __attribute__((aligned(16)));
        #pragma unroll
        for (int i = 0; i < 8; ++i) {
            float f;
            if (ks == 0) { int k = 8 * (lane >> 4) + i; f = wi[u * V + k]; }
            else         { int k = (ks - 1) * 32 + 8 * (lane >> 4) + i; f = wh[u * 256 + k]; }
            v[i] = f2bf(f * scl);
        }
        *(int4*)(wFrag + (size_t)idx * 8) = *(const int4*)v;
    } else if (idx < 13824 + 4096) {
        int pidx = idx - 13824;
        int lane = pidx & 63;
        int rest = pidx >> 6;
        int ct2 = rest & 15;
        int ks = rest >> 4;
        int sel = ct2 >> 3, tl = ct2 & 7;
        int u = tl * 16 + (lane & 15);
        const float* wsrc = sel ? lv_w : mu_w;
        unsigned short v[8] __attribute__((aligned(16)));
        #pragma unroll
        for (int i = 0; i < 8; ++i) {
            int k = ks * 32 + 8 * (lane >> 4) + i;
            v[i] = f2bf(wsrc[u * H + k]);
        }
        *(int4*)(pFrag + (size_t)pidx * 8) = *(const int4*)v;
    }
    if (idx < 6 * H) {
        int s = idx / H, u = idx % H;
        float val;
        if (s == 0)      val = (wir_b[u] + whr_b[u]) * -1.44269504f;
        else if (s == 1) val = (wiz_b[u] + whz_b[u]) * -1.44269504f;
        else if (s == 2) val = win_b[u] * 2.88539008f;
        else if (s == 3) val = whn_b[u] * 2.88539008f;
        else if (s == 4) val = mu_b[u];
        else             val = lv_b[u];
        bias[idx] = val;
    }
}

// ---------------------------------------------------------------------------
// M=32 GRU tile body, weights loaded at use (L2-hot). For the wide,
// occupancy-bound subtree kernel. Per wave: 8 f32x4 acc.
// ---------------------------------------------------------------------------
template <typename EMIT>
__device__ __forceinline__ void gru32_body(
    const unsigned short* __restrict__ wFrag, const float* __restrict__ bias,
    bf16x8 x0, bf16x8 x1, float m0, float m1,
    const unsigned short* __restrict__ hin,
    int lane, int w, EMIT emit)
{
    const int l15 = lane & 15;
    const int lg = lane >> 4;
    const int u0 = w * 16 + lg * 4;

    f32x4 acc_r[2], acc_z[2], acc_i[2], acc_h[2];
    {
        f32x4 b0 = *(const f32x4*)(bias + u0);
        f32x4 b1 = *(const f32x4*)(bias + 128 + u0);
        f32x4 b2 = *(const f32x4*)(bias + 256 + u0);
        f32x4 b3 = *(const f32x4*)(bias + 384 + u0);
        acc_r[0] = b0; acc_r[1] = b0;
        acc_z[0] = b1; acc_z[1] = b1;
        acc_i[0] = b2; acc_i[1] = b2;
        acc_h[0] = b3; acc_h[1] = b3;
    }
    {
        bf16x8 wr_ = *(const bf16x8*)(wFrag + ((size_t)(w) * 64 + lane) * 8);
        bf16x8 wz_ = *(const bf16x8*)(wFrag + ((size_t)(8 + w) * 64 + lane) * 8);
        bf16x8 wn_ = *(const bf16x8*)(wFrag + ((size_t)(16 + w) * 64 + lane) * 8);
        acc_r[0] = mfma_wx(wr_, x0, acc_r[0]);
        acc_r[1] = mfma_wx(wr_, x1, acc_r[1]);
        acc_z[0] = mfma_wx(wz_, x0, acc_z[0]);
        acc_z[1] = mfma_wx(wz_, x1, acc_z[1]);
        acc_i[0] = mfma_wx(wn_, x0, acc_i[0]);
        acc_i[1] = mfma_wx(wn_, x1, acc_i[1]);
    }
    #pragma unroll 2
    for (int ks = 1; ks <= 8; ++ks) {
        bf16x8 a0 = *(const bf16x8*)(&hin[l15 * LDH + (ks - 1) * 32 + 8 * lg]);
        bf16x8 a1 = *(const bf16x8*)(&hin[(16 + l15) * LDH + (ks - 1) * 32 + 8 * lg]);
        size_t fb = (size_t)ks * 24 * 64;
        bf16x8 wr_ = *(const bf16x8*)(wFrag + (fb + (size_t)(w) * 64 + lane) * 8);
        bf16x8 wz_ = *(const bf16x8*)(wFrag + (fb + (size_t)(8 + w) * 64 + lane) * 8);
        bf16x8 wn_ = *(const bf16x8*)(wFrag + (fb + (size_t)(16 + w) * 64 + lane) * 8);
        acc_r[0] = mfma_wx(wr_, a0, acc_r[0]);
        acc_r[1] = mfma_wx(wr_, a1, acc_r[1]);
        acc_z[0] = mfma_wx(wz_, a0, acc_z[0]);
        acc_z[1] = mfma_wx(wz_, a1, acc_z[1]);
        acc_h[0] = mfma_wx(wn_, a0, acc_h[0]);
        acc_h[1] = mfma_wx(wn_, a1, acc_h[1]);
    }
    #pragma unroll
    for (int rt = 0; rt < 2; ++rt) {
        float m = rt ? m1 : m0;
        int hrow = rt * 16 + l15;
        ushort4 h1v = *(const ushort4*)(&hin[hrow * LDH + u0]);
        ushort4 h2v = *(const ushort4*)(&hin[hrow * LDH + 128 + u0]);
        const unsigned short* h1p = (const unsigned short*)&h1v;
        const unsigned short* h2p = (const unsigned short*)&h2v;
        float ho[4];
        #pragma unroll
        for (int reg = 0; reg < 4; ++reg) {
            float rg = sig_pre(acc_r[rt][reg]);
            float zg = sig_pre(acc_z[rt][reg]);
            float cg = tanh_pre(acc_i[rt][reg] + rg * acc_h[rt][reg]);
            float hm = 0.5f * bf2f(h1p[reg]) + 0.5f * bf2f(h2p[reg]);
            ho[reg] = (cg + zg * (hm - cg)) * m;
        }
        emit(rt, u0, pack4(ho[0], ho[1], ho[2], ho[3]));
    }
}

// ---------------------------------------------------------------------------
// Load this wave's 27 weight frags into registers (for latency-bound tail).
// ---------------------------------------------------------------------------
__device__ __forceinline__ void load_wreg(
    const unsigned short* __restrict__ wFrag, int lane, int w,
    bf16x8 (&wr)[9], bf16x8 (&wz)[9], bf16x8 (&wn)[9])
{
    #pragma unroll
    for (int ks = 0; ks < 9; ++ks) {
        size_t fb = (size_t)ks * 24 * 64;
        wr[ks] = *(const bf16x8*)(wFrag + (fb + (size_t)(w) * 64 + lane) * 8);
        wz[ks] = *(const bf16x8*)(wFrag + (fb + (size_t)(8 + w) * 64 + lane) * 8);
        wn[ks] = *(const bf16x8*)(wFrag + (fb + (size_t)(16 + w) * 64 + lane) * 8);
    }
}

// ---------------------------------------------------------------------------
// M=32 GRU tile body, weights-stationary (registers). For the tail.
// ---------------------------------------------------------------------------
template <typename EMIT>
__device__ __forceinline__ void gru32_ws(
    const bf16x8 (&wr)[9], const bf16x8 (&wz)[9], const bf16x8 (&wn)[9],
    const float* __restrict__ bias,
    bf16x8 x0, bf16x8 x1, float m0, float m1,
    const unsigned short* __restrict__ hin,
    int lane, int w, EMIT emit)
{
    const int l15 = lane & 15;
    const int lg = lane >> 4;
    const int u0 = w * 16 + lg * 4;

    f32x4 acc_r[2], acc_z[2], acc_i[2], acc_h[2];
    {
        f32x4 b0 = *(const f32x4*)(bias + u0);
        f32x4 b1 = *(const f32x4*)(bias + 128 + u0);
        f32x4 b2 = *(const f32x4*)(bias + 256 + u0);
        f32x4 b3 = *(const f32x4*)(bias + 384 + u0);
        acc_r[0] = b0; acc_r[1] = b0;
        acc_z[0] = b1; acc_z[1] = b1;
        acc_i[0] = b2; acc_i[1] = b2;
        acc_h[0] = b3; acc_h[1] = b3;
    }
    acc_r[0] = mfma_wx(wr[0], x0, acc_r[0]);
    acc_r[1] = mfma_wx(wr[0], x1, acc_r[1]);
    acc_z[0] = mfma_wx(wz[0], x0, acc_z[0]);
    acc_z[1] = mfma_wx(wz[0], x1, acc_z[1]);
    acc_i[0] = mfma_wx(wn[0], x0, acc_i[0]);
    acc_i[1] = mfma_wx(wn[0], x1, acc_i[1]);
    #pragma unroll
    for (int ks = 1; ks <= 8; ++ks) {
        bf16x8 a0 = *(const bf16x8*)(&hin[l15 * LDH + (ks - 1) * 32 + 8 * lg]);
        bf16x8 a1 = *(const bf16x8*)(&hin[(16 + l15) * LDH + (ks - 1) * 32 + 8 * lg]);
        acc_r[0] = mfma_wx(wr[ks], a0, acc_r[0]);
        acc_r[1] = mfma_wx(wr[ks], a1, acc_r[1]);
        acc_z[0] = mfma_wx(wz[ks], a0, acc_z[0]);
        acc_z[1] = mfma_wx(wz[ks], a1, acc_z[1]);
        acc_h[0] = mfma_wx(wn[ks], a0, acc_h[0]);
        acc_h[1] = mfma_wx(wn[ks], a1, acc_h[1]);
    }
    #pragma unroll
    for (int rt = 0; rt < 2; ++rt) {
        float m = rt ? m1 : m0;
        int hrow = rt * 16 + l15;
        ushort4 h1v = *(const ushort4*)(&hin[hrow * LDH + u0]);
        ushort4 h2v = *(const ushort4*)(&hin[hrow * LDH + 128 + u0]);
        const unsigned short* h1p = (const unsigned short*)&h1v;
        const unsigned short* h2p = (const unsigned short*)&h2v;
        float ho[4];
        #pragma unroll
        for (int reg = 0; reg < 4; ++reg) {
            float rg = sig_pre(acc_r[rt][reg]);
            float zg = sig_pre(acc_z[rt][reg]);
            float cg = tanh_pre(acc_i[rt][reg] + rg * acc_h[rt][reg]);
            float hm = 0.5f * bf2f(h1p[reg]) + 0.5f * bf2f(h2p[reg]);
            ho[reg] = (cg + zg * (hm - cg)) * m;
        }
        emit(rt, u0, pack4(ho[0], ho[1], ho[2], ho[3]));
    }
}

// ---------------------------------------------------------------------------
// Fused subtree kernel (R13 form): levels leaf+9+8, 512 thr, weights from L2,
// occupancy 4 blocks/CU. Grid 1024: block (n = d8 node, q = 32-row chunk).
// ---------------------------------------------------------------------------
__global__ __launch_bounds__(NT, 4) void subtree8_kernel(
    const float* __restrict__ targets, const float* __restrict__ masks,
    unsigned short* __restrict__ lvl8,
    const unsigned short* __restrict__ wFrag, const float* __restrict__ bias)
{
    __shared__ __attribute__((aligned(16))) unsigned short h_lds[32 * LDH];
    __shared__ __attribute__((aligned(16))) unsigned short h2_lds[32 * LDH];

    const int tid = threadIdx.x;
    const int lane = tid & 63;
    const int w = tid >> 6;
    const int l15 = lane & 15;
    const int lg = lane >> 4;
    const int u0 = w * 16 + lg * 4;
    const int n = blockIdx.x >> 2;
    const int q = blockIdx.x & 3;

    for (int half = 0; half < 2; ++half) {
        const int j = 2 * n + half;
        const size_t r9 = (size_t)(511 + j) * B + (size_t)q * 32;

        // ---- leaf children of j -> h_lds (K0 only; h1=h2=0) ----
        #pragma unroll
        for (int c = 0; c < 2; ++c) {
            const size_t crow = (size_t)(1023 + 2 * j + c) * B + (size_t)q * 32;
            bf16x8 xf0 = load_xfrag(targets + (crow + l15) * V + 8 * lg);
            bf16x8 xf1 = load_xfrag(targets + (crow + 16 + l15) * V + 8 * lg);
            float m0 = masks[crow + l15];
            float m1 = masks[crow + 16 + l15];
            f32x4 ar[2], az[2], an[2], bh;
            {
                f32x4 b0 = *(const f32x4*)(bias + u0);
                f32x4 b1 = *(const f32x4*)(bias + 128 + u0);
                f32x4 b2 = *(const f32x4*)(bias + 256 + u0);
                bh       = *(const f32x4*)(bias + 384 + u0);
                ar[0] = b0; ar[1] = b0;
                az[0] = b1; az[1] = b1;
                an[0] = b2; an[1] = b2;
            }
            {
                bf16x8 wr_ = *(const bf16x8*)(wFrag + ((size_t)(w) * 64 + lane) * 8);
                bf16x8 wz_ = *(const bf16x8*)(wFrag + ((size_t)(8 + w) * 64 + lane) * 8);
                bf16x8 wn_ = *(const bf16x8*)(wFrag + ((size_t)(16 + w) * 64 + lane) * 8);
                ar[0] = mfma_wx(wr_, xf0, ar[0]);
                ar[1] = mfma_wx(wr_, xf1, ar[1]);
                az[0] = mfma_wx(wz_, xf0, az[0]);
                az[1] = mfma_wx(wz_, xf1, az[1]);
                an[0] = mfma_wx(wn_, xf0, an[0]);
                an[1] = mfma_wx(wn_, xf1, an[1]);
            }
            #pragma unroll
            for (int rt = 0; rt < 2; ++rt) {
                float m = rt ? m1 : m0;
                int row = rt * 16 + l15;
                float ho[4];
                #pragma unroll
                for (int reg = 0; reg < 4; ++reg) {
                    float rg = sig_pre(ar[rt][reg]);
                    float zg = sig_pre(az[rt][reg]);
                    float cg = tanh_pre(an[rt][reg] + rg * bh[reg]);
                    ho[reg] = (cg - zg * cg) * m;
                }
                *(uint2*)(&h_lds[row * LDH + c * 128 + u0]) = pack4(ho[0], ho[1], ho[2], ho[3]);
            }
        }
        __syncthreads();   // h_lds (leaf h) ready

        // ---- d9 tile: out -> h2_lds ----
        {
            bf16x8 x9_0 = load_xfrag(targets + (r9 + l15) * V + 8 * lg);
            bf16x8 x9_1 = load_xfrag(targets + (r9 + 16 + l15) * V + 8 * lg);
            float m0 = masks[r9 + l15];
            float m1 = masks[r9 + 16 + l15];
            gru32_body(wFrag, bias, x9_0, x9_1, m0, m1, h_lds, lane, w,
                [&](int rt, int uu, uint2 pk) {
                    int row = rt * 16 + l15;
                    *(uint2*)(&h2_lds[row * LDH + half * 128 + uu]) = pk;
                });
        }
        __syncthreads();   // d9 reads of h_lds done; h2 half visible
    }

    // ---- d8 tile: x8 + h2_lds -> global lvl8 ----
    {
        const size_t r8 = (size_t)(255 + n) * B + (size_t)q * 32;
        bf16x8 x8_0 = load_xfrag(targets + (r8 + l15) * V + 8 * lg);
        bf16x8 x8_1 = load_xfrag(targets + (r8 + 16 + l15) * V + 8 * lg);
        float m0 = masks[r8 + l15];
        float m1 = masks[r8 + 16 + l15];
        gru32_body(wFrag, bias, x8_0, x8_1, m0, m1, h2_lds, lane, w,
            [&](int rt, int uu, uint2 pk) {
                int row = rt * 16 + l15;
                *(uint2*)(lvl8 + ((size_t)n * B + (size_t)q * 32 + row) * H + uu) = pk;
            });
    }
}

// ---------------------------------------------------------------------------
// tail4 (R14 form): 4 tree levels dtop..dtop-3 per (subtree root, 16-row
// chunk), chained through LDS, weights-stationary. Grid = (1<<(dtop-3))*8.
// ---------------------------------------------------------------------------
__global__ __launch_bounds__(NT, 2) void tail4_kernel(
    const float* __restrict__ targets, const float* __restrict__ masks,
    const unsigned short* __restrict__ prev,     // level dtop+1 buffer
    unsigned short* __restrict__ outg,           // level dtop-3 buffer or null
    int s3, int s2, int s1, int s0,
    const unsigned short* __restrict__ wFrag, const float* __restrict__ bias,
    int do_proj, const unsigned short* __restrict__ pFrag, float* __restrict__ proj_out)
{
    __shared__ __attribute__((aligned(16))) unsigned short hc[32 * LDH];       // staging / proj input
    __shared__ __attribute__((aligned(16))) unsigned short h6[2 * 32 * LDH];   // dtop outputs
    __shared__ __attribute__((aligned(16))) unsigned short h5[32 * LDH];       // dtop-1 outputs
    __shared__ __attribute__((aligned(16))) unsigned short h4[16 * LDH];       // dtop-2 outputs

    const int tid = threadIdx.x;
    const int lane = tid & 63;
    const int w = tid >> 6;
    const int l15 = lane & 15;
    const int lg = lane >> 4;
    const int u0 = w * 16 + lg * 4;
    const int pr = blockIdx.x >> 3;
    const int c8 = blockIdx.x & 7;

    bf16x8 wr[9], wz[9], wn[9];
    load_wreg(wFrag, lane, w, wr, wz, wn);

    // ---- Phase 1: 4 x (stage from prev -> dtop M=32 tile -> h6) ----
    for (int s = 0; s < 4; ++s) {
        const int l1 = 4 * pr + s;   // node at level dtop-1
        #pragma unroll
        for (int t = 0; t < 2; ++t) {
            int task = t * NT + tid;
            int row = task >> 5;
            int ck = task & 31;
            int g = 4 * l1 + 2 * (row >> 4) + (ck >> 4);
            int4 v = *(const int4*)(prev + (((size_t)g) * B + (size_t)c8 * 16 + (row & 15)) * H + (ck & 15) * 8);
            *(int4*)(&hc[row * LDH + ck * 8]) = v;
        }
        size_t xr0 = ((size_t)(s3 + 2 * l1)) * B + (size_t)c8 * 16 + l15;
        size_t xr1 = ((size_t)(s3 + 2 * l1 + 1)) * B + (size_t)c8 * 16 + l15;
        bf16x8 xc0 = load_xfrag(targets + xr0 * V + 8 * lg);
        bf16x8 xc1 = load_xfrag(targets + xr1 * V + 8 * lg);
        float m0 = masks[xr0];
        float m1 = masks[xr1];
        __syncthreads();
        unsigned short* hout = h6 + (size_t)(s >> 1) * 32 * LDH;
        int rowbase = 16 * (s & 1);
        gru32_ws(wr, wz, wn, bias, xc0, xc1, m0, m1, hc, lane, w,
            [&](int rt, int uu, uint2 pk) {
                *(uint2*)(&hout[(rowbase + l15) * LDH + rt * 128 + uu]) = pk;
            });
        __syncthreads();
    }

    // ---- Phase 2: 2 x (dtop-1 M=32 tile: h6[k] -> h5) ----
    for (int k = 0; k < 2; ++k) {
        int n1 = 4 * pr + 2 * k;
        size_t xr0 = ((size_t)(s2 + n1)) * B + (size_t)c8 * 16 + l15;
        size_t xr1 = ((size_t)(s2 + n1 + 1)) * B + (size_t)c8 * 16 + l15;
        bf16x8 xc0 = load_xfrag(targets + xr0 * V + 8 * lg);
        bf16x8 xc1 = load_xfrag(targets + xr1 * V + 8 * lg);
        float m0 = masks[xr0];
        float m1 = masks[xr1];
        const unsigned short* hin = h6 + (size_t)k * 32 * LDH;
        int rowbase = 16 * k;
        gru32_ws(wr, wz, wn, bias, xc0, xc1, m0, m1, hin, lane, w,
            [&](int rt, int uu, uint2 pk) {
                *(uint2*)(&h5[(rowbase + l15) * LDH + rt * 128 + uu]) = pk;
            });
    }
    __syncthreads();

    // ---- Phase 3: dtop-2 M=32 tile: h5 -> h4 ----
    {
        size_t xr0 = ((size_t)(s1 + 2 * pr)) * B + (size_t)c8 * 16 + l15;
        size_t xr1 = ((size_t)(s1 + 2 * pr + 1)) * B + (size_t)c8 * 16 + l15;
        bf16x8 xc0 = load_xfrag(targets + xr0 * V + 8 * lg);
        bf16x8 xc1 = load_xfrag(targets + xr1 * V + 8 * lg);
        float m0 = masks[xr0];
        float m1 = masks[xr1];
        gru32_ws(wr, wz, wn, bias, xc0, xc1, m0, m1, h5, lane, w,
            [&](int rt, int uu, uint2 pk) {
                *(uint2*)(&h4[l15 * LDH + rt * 128 + uu]) = pk;
            });
    }
    __syncthreads();

    // ---- Phase 4: dtop-3 M=16 tile: h4 -> outg / proj input ----
    {
        size_t xrp = ((size_t)(s0 + pr)) * B + (size_t)c8 * 16 + l15;
        bf16x8 xp = load_xfrag(targets + xrp * V + 8 * lg);
        float m = masks[xrp];
        f32x4 acc_r = *(const f32x4*)(bias + u0);
        f32x4 acc_z = *(const f32x4*)(bias + 128 + u0);
        f32x4 acc_i = *(const f32x4*)(bias + 256 + u0);
        f32x4 acc_h = *(const f32x4*)(bias + 384 + u0);
        acc_r = mfma_wx(wr[0], xp, acc_r);
        acc_z = mfma_wx(wz[0], xp, acc_z);
        acc_i = mfma_wx(wn[0], xp, acc_i);
        #pragma unroll
        for (int ks = 1; ks <= 8; ++ks) {
            bf16x8 a = *(const bf16x8*)(&h4[l15 * LDH + (ks - 1) * 32 + 8 * lg]);
            acc_r = mfma_wx(wr[ks], a, acc_r);
            acc_z = mfma_wx(wz[ks], a, acc_z);
            acc_h = mfma_wx(wn[ks], a, acc_h);
        }
        ushort4 h1v = *(const ushort4*)(&h4[l15 * LDH + u0]);
        ushort4 h2v = *(const ushort4*)(&h4[l15 * LDH + 128 + u0]);
        const unsigned short* h1p = (const unsigned short*)&h1v;
        const unsigned short* h2p = (const unsigned short*)&h2v;
        float ho[4];
        #pragma unroll
        for (int reg = 0; reg < 4; ++reg) {
            float rg = sig_pre(acc_r[reg]);
            float zg = sig_pre(acc_z[reg]);
            float cg = tanh_pre(acc_i[reg] + rg * acc_h[reg]);
            float hm = 0.5f * bf2f(h1p[reg]) + 0.5f * bf2f(h2p[reg]);
            ho[reg] = (cg + zg * (hm - cg)) * m;
        }
        uint2 pk = pack4(ho[0], ho[1], ho[2], ho[3]);
        if (outg)
            *(uint2*)(outg + ((size_t)pr * B + (size_t)c8 * 16 + l15) * H + u0) = pk;
        if (do_proj)
            *(uint2*)(&hc[l15 * LDH + u0]) = pk;   // hc is dead; race-free proj input
    }

    if (do_proj) {
        __syncthreads();
        f32x4 pa[2];
        #pragma unroll
        for (int jj = 0; jj < 2; ++jj) {
            int ct2 = 2 * w + jj;
            int sel = ct2 >> 3, tl = ct2 & 7;
            pa[jj] = *(const f32x4*)(bias + 512 + sel * 128 + tl * 16 + lg * 4);
        }
        #pragma unroll
        for (int ks = 0; ks < 4; ++ks) {
            bf16x8 a = *(const bf16x8*)(&hc[l15 * LDH + ks * 32 + 8 * lg]);
            #pragma unroll
            for (int jj = 0; jj < 2; ++jj) {
                bf16x8 f = *(const bf16x8*)(pFrag + (((size_t)ks * 16 + 2 * w + jj) * 64 + lane) * 8);
                pa[jj] = mfma_wx(f, a, pa[jj]);
            }
        }
        #pragma unroll
        for (int jj = 0; jj < 2; ++jj) {
            int ct2 = 2 * w + jj;
            int sel = ct2 >> 3, tl = ct2 & 7;
            int up = tl * 16 + lg * 4;
            int row = c8 * 16 + l15;
            *(f32x4*)(proj_out + ((size_t)sel * B + row) * H + up) = pa[jj];
        }
    }
}

// ---------------------------------------------------------------------------
extern "C" void kernel_launch(void* const* d_in, const int* in_sizes, int n_in,
                              void* d_out, int out_size, void* d_ws, size_t ws_size,
                              hipStream_t stream)
{
    const float* targets = (const float*)d_in[0];
    const float* masks   = (const float*)d_in[1];
    const float* wir_w = (const float*)d_in[2];  const float* wir_b = (const float*)d_in[3];
    const float* whr_w = (const float*)d_in[4];  const float* whr_b = (const float*)d_in[5];
    const float* wiz_w = (const float*)d_in[6];  const float* wiz_b = (const float*)d_in[7];
    const float* whz_w = (const float*)d_in[8];  const float* whz_b = (const float*)d_in[9];
    const float* win_w = (const float*)d_in[10]; const float* win_b = (const float*)d_in[11];
    const float* whn_w = (const float*)d_in[12]; const float* whn_b = (const float*)d_in[13];
    const float* mu_w  = (const float*)d_in[14]; const float* mu_b  = (const float*)d_in[15];
    const float* lv_w  = (const float*)d_in[16]; const float* lv_b  = (const float*)d_in[17];

    unsigned short* ws16 = (unsigned short*)d_ws;
    unsigned short* lvl8 = ws16;                               // 256*128*128
    unsigned short* lvl4 = lvl8 + (size_t)256 * B * H;         // 16*128*128
    unsigned short* wFrag = lvl4 + (size_t)16 * B * H;         // 110592 bf16
    unsigned short* pFrag = wFrag + 110592;                    // 32768 bf16
    float*          biasw = (float*)(pFrag + 32768);           // 768 fp32

    prep_pack<<<70, 256, 0, stream>>>(
        wir_w, whr_w, wiz_w, whz_w, win_w, whn_w,
        wir_b, whr_b, wiz_b, whz_b, win_b, whn_b,
        mu_w, mu_b, lv_w, lv_b, wFrag, pFrag, biasw);

    subtree8_kernel<<<1024, NT, 0, stream>>>(targets, masks, lvl8, wFrag, biasw);

    // levels 7..4 (lvl8 -> lvl4), only lvl4 materialized
    tail4_kernel<<<128, NT, 0, stream>>>(
        targets, masks, lvl8, lvl4, 127, 63, 31, 15,
        wFrag, biasw, 0, nullptr, nullptr);

    // levels 3..0 + fused projection (lvl4 -> d_out)
    tail4_kernel<<<8, NT, 0, stream>>>(
        targets, masks, lvl4, nullptr, 7, 3, 1, 0,
        wFrag, biasw, 1, pFrag, (float*)d_out);
}